// Round 12
// baseline (150.070 us; speedup 1.0000x reference)
//
#include <hip/hip_runtime.h>
#include <hip/hip_bf16.h>

typedef unsigned short u16;
typedef __attribute__((ext_vector_type(8))) short short8;
typedef __attribute__((ext_vector_type(4))) float f32x4;
typedef __attribute__((ext_vector_type(16))) float f32x16;
typedef __attribute__((ext_vector_type(4))) unsigned short u16x4;

#define DEVINL __device__ __forceinline__

DEVINL u16 f2bf(float f) {
    union { float f; unsigned u; } x; x.f = f;
    unsigned u = x.u;
    u += 0x7fffu + ((u >> 16) & 1u);   // round-to-nearest-even
    return (u16)(u >> 16);
}

DEVINL void gload_lds16(const void* g, void* l) {
    __builtin_amdgcn_global_load_lds(
        (const __attribute__((address_space(1))) unsigned*)g,
        (__attribute__((address_space(3))) unsigned*)l, 16, 0, 0);
}

// XOR swizzle for 128B-stride LDS rows: spreads 16B slots across banks.
DEVINL int swz(int row) { return (((row & 7) ^ ((row >> 3) & 7)) << 4); }

// v_permlane32_swap: after call, for lane<32: a=own a, b=partner's a;
// for lane>=32: a=partner's b, b=own b.
DEVINL void swap32(unsigned& a, unsigned& b) {
#if __has_builtin(__builtin_amdgcn_permlane32_swap)
    typedef __attribute__((ext_vector_type(2))) unsigned uv2;
    uv2 r = __builtin_amdgcn_permlane32_swap(a, b, false, false);
    a = r.x; b = r.y;
#else
    int h = ((int)(threadIdx.x & 63)) >> 5;
    unsigned pa = (unsigned)__shfl_xor((int)a, 32);
    unsigned pb = (unsigned)__shfl_xor((int)b, 32);
    unsigned na = h ? pb : a;
    unsigned nb = h ? b : pa;
    a = na; b = nb;
#endif
}

// ---------------- convert x (fp32 -> bf16), vectorized ----------------
__global__ void k_conv_x(const float* __restrict__ in, u16* __restrict__ out, int n4) {
    int i = blockIdx.x * blockDim.x + threadIdx.x;
    int stride = gridDim.x * blockDim.x;
    for (; i < n4; i += stride) {
        float4 v = ((const float4*)in)[i];
        u16x4 o;
        o.x = f2bf(v.x); o.y = f2bf(v.y); o.z = f2bf(v.z); o.w = f2bf(v.w);
        ((u16x4*)out)[i] = o;
    }
}

// ---------------- transpose + convert: in [R][C] fp32 -> out [C][R] bf16 ----------------
__global__ void k_transpose_bf(const float* __restrict__ in, u16* __restrict__ out, int R, int C) {
    __shared__ float t[32][33];
    int c0 = blockIdx.x * 32, r0 = blockIdx.y * 32;
    int tx = threadIdx.x, ty = threadIdx.y;
    #pragma unroll
    for (int j = 0; j < 32; j += 8)
        t[ty + j][tx] = in[(size_t)(r0 + ty + j) * C + c0 + tx];
    __syncthreads();
    #pragma unroll
    for (int j = 0; j < 32; j += 8)
        out[(size_t)(c0 + ty + j) * R + r0 + tx] = f2bf(t[tx][ty + j]);
}

// ---------------- GEMM: 256x256, BK=64, R8-style free-running 2-phase pipeline --------
// C[M][N] = A[M][K] @ BT[N][K]^T, bf16 in, bf16/f32 out.
// 8 waves (2M x 4N), per-wave 128x64 -> LDS-read bytes/FLOP 33% lower than 64x64.
// Double-buffered LDS (2 x 64KB = 128KB -> 1 block/CU, 2 waves/SIMD).
// Per K-step of 64: stage(t+1) FIRST (overlaps compute), ds_reads + 64 MFMA
// (compiler-scheduled lgkm interleave, waves drift freely), ONE vmcnt(0) + barrier.
// R11 post-mortem: 128^2 tile is LDS-BW-bound (~95% LDS pipe); this cuts LDS/FLOP.
template<bool OUT_BF16>
__global__ __launch_bounds__(512, 2)
void k_gemmL(const u16* __restrict__ A, const u16* __restrict__ BT,
             void* __restrict__ C, int N, int K) {
    __shared__ char lds[2 * 65536];    // per buf: A @0 (32KB), B @32768 (32KB)

    const int tid  = threadIdx.x;
    const int lane = tid & 63;
    const int lo   = lane & 15;
    const int hi   = lane >> 4;
    const int wave = tid >> 6;
    const int wm   = wave >> 2;        // 0..1 (128-row band)
    const int wn   = wave & 3;         // 0..3 (64-col band)

    // XCD-aware bijective block swizzle (nwg % 8 == 0 for our grids)
    const int gx   = gridDim.x;
    const int nwg  = gx * gridDim.y;
    const int orig = blockIdx.y * gx + blockIdx.x;
    const int wg   = (orig & 7) * (nwg >> 3) + (orig >> 3);
    const long row0 = (long)(wg / gx) * 256;
    const long col0 = (long)(wg % gx) * 256;

    const int NT = K >> 6;             // BK = 64

    const int srow = tid >> 3;                         // 0..63 (row within 64-row chunk)
    const int gsb  = ((tid & 7) ^ (srow & 7)) << 4;    // pre-swizzled source byte

    auto stage = [&](int t) {
        char* base = lds + (t & 1) * 65536;
        #pragma unroll
        for (int c = 0; c < 4; c++)
            gload_lds16((const char*)(A + (row0 + c * 64 + srow) * (size_t)K + t * 64) + gsb,
                        base + c * 8192 + tid * 16);
        #pragma unroll
        for (int c = 0; c < 4; c++)
            gload_lds16((const char*)(BT + (col0 + c * 64 + srow) * (size_t)K + t * 64) + gsb,
                        base + 32768 + c * 8192 + tid * 16);
    };

    f32x4 acc[8][4] = {};

    stage(0);
    asm volatile("s_waitcnt vmcnt(0)" ::: "memory");
    __builtin_amdgcn_s_barrier();

    for (int t = 0; t < NT; t++) {
        if (t + 1 < NT) stage(t + 1);               // issue early: hides under MFMA
        const char* ab = lds + (t & 1) * 65536;
        const char* bb = ab + 32768;
        #pragma unroll
        for (int kk = 0; kk < 2; kk++) {
            short8 af[8], bf[4];
            #pragma unroll
            for (int m = 0; m < 8; m++) {
                int r = wm * 128 + m * 16 + lo;
                af[m] = *(const short8*)(ab + r * 128 + ((kk * 64 + hi * 16) ^ ((r & 7) << 4)));
            }
            #pragma unroll
            for (int n = 0; n < 4; n++) {
                int r = wn * 64 + n * 16 + lo;
                bf[n] = *(const short8*)(bb + r * 128 + ((kk * 64 + hi * 16) ^ ((r & 7) << 4)));
            }
            #pragma unroll
            for (int m = 0; m < 8; m++)
                #pragma unroll
                for (int n = 0; n < 4; n++)
                    acc[m][n] = __builtin_amdgcn_mfma_f32_16x16x32_bf16(af[m], bf[n], acc[m][n], 0, 0, 0);
        }
        if (t + 1 < NT) {
            asm volatile("s_waitcnt vmcnt(0)" ::: "memory");   // t+1 resident
            __builtin_amdgcn_s_barrier();                      // all reads of buf[t] done
        }
    }

    // ---- epilogue ----
    #pragma unroll
    for (int m = 0; m < 8; m++)
        #pragma unroll
        for (int n = 0; n < 4; n++)
            #pragma unroll
            for (int r = 0; r < 4; r++) {
                long row = row0 + wm * 128 + m * 16 + hi * 4 + r;
                long col = col0 + wn * 64 + n * 16 + lo;
                if constexpr (OUT_BF16)
                    ((u16*)C)[row * (size_t)N + col] = f2bf(acc[m][n][r]);
                else
                    ((float*)C)[row * (size_t)N + col] = acc[m][n][r];
            }
}

// ---------------- Flash attention v4: swapped-operand 32x32 + double-buffered K/V ------
// grid: 1024 blocks (8 qi x 128 bh), longest-first. Block = 4 waves x 32 q-rows = 128 q.
#define SCALE_L2E 0.18033688011112042f  // (1/sqrt(64)) * log2(e)

__global__ __launch_bounds__(256, 2)
void k_attn(const u16* __restrict__ qkv, u16* __restrict__ y) {
    constexpr int S = 1024, E = 1024, TE = 3072;
    __shared__ char alds[2 * 16384];   // per buf: K @0 (8KB, [kv][d] swz), V @8192 ([d][kv] swz)

    const int tid  = threadIdx.x;
    const int lane = tid & 63;
    const int l31  = lane & 31;
    const int hA   = lane >> 5;
    const int wave = tid >> 6;

    const int qi = 7 - (int)(blockIdx.x >> 7);   // longest first
    const int bh = blockIdx.x & 127;
    const int b  = bh >> 4;
    const int h  = bh & 15;
    const int q0 = qi * 128;
    const size_t rowbase = (size_t)b * S;
    const int qg = q0 + wave * 32 + l31;         // this lane's q-row

    short8 qf[4];
    {
        const u16* qp = qkv + (rowbase + qg) * TE + h * 64 + hA * 8;
        #pragma unroll
        for (int kd = 0; kd < 4; kd++) qf[kd] = *(const short8*)(qp + kd * 16);
    }

    f32x16 o0 = {}, o1 = {};
    float ms = -1e30f, lsum = 0.f;

    const int kr0 = (wave << 3) + (lane >> 3);
    const int kcb = (lane & 7) * 16;
    const int vkv = (tid >> 3) * 2;
    const int vdc = (tid & 7) * 8;

    auto stage = [&](int t) {
        char* base = alds + (t & 1) * 16384;
        const int kv0 = t * 64;
        #pragma unroll
        for (int it = 0; it < 2; it++) {
            int r = kr0 + it * 32;
            const char* src = (const char*)qkv
                + (((rowbase + kv0 + r) * TE + E + h * 64) << 1) + (kcb ^ swz(r));
            gload_lds16(src, base + wave * 1024 + it * 4096);
        }
        const u16* vsrc = qkv + (rowbase + kv0 + vkv) * TE + 2 * E + h * 64 + vdc;
        short8 v0 = *(const short8*)vsrc;
        short8 v1 = *(const short8*)(vsrc + TE);
        #pragma unroll
        for (int j = 0; j < 8; j++) {
            int d = vdc + j;
            unsigned val = (unsigned)(u16)v0[j] | ((unsigned)(u16)v1[j] << 16);
            *(unsigned*)(base + 8192 + d * 128 + ((vkv * 2) ^ swz(d))) = val;
        }
    };

    const int ntiles = 2 * qi + 2;
    stage(0);
    for (int t = 0; t < ntiles; ++t) {
        __syncthreads();                       // buf[t] resident; prior reads done
        if (t + 1 < ntiles) stage(t + 1);      // overlaps with compute(t)

        const char* Kt = alds + (t & 1) * 16384;
        const char* Vt = Kt + 8192;
        const int kv0 = t * 64;

        const bool active = (kv0 <= q0 + wave * 32 + 31);
        if (!active) continue;   // wave-uniform; still hits next iter's barrier

        f32x16 s0 = {}, s1 = {};
        #pragma unroll
        for (int kd = 0; kd < 4; kd++) {
            int r0 = l31, r1 = 32 + l31;
            short8 ka0 = *(const short8*)(Kt + r0 * 128 + ((kd * 32 + hA * 16) ^ swz(r0)));
            short8 ka1 = *(const short8*)(Kt + r1 * 128 + ((kd * 32 + hA * 16) ^ swz(r1)));
            s0 = __builtin_amdgcn_mfma_f32_32x32x16_bf16(ka0, qf[kd], s0, 0, 0, 0);
            s1 = __builtin_amdgcn_mfma_f32_32x32x16_bf16(ka1, qf[kd], s1, 0, 0, 0);
        }

        if (kv0 + 63 > q0 + wave * 32) {
            #pragma unroll
            for (int r = 0; r < 16; r++) {
                int kvr = kv0 + ((r & 3) + 8 * (r >> 2) + 4 * hA);
                if (kvr > qg)      s0[r] = -1e30f;
                if (kvr + 32 > qg) s1[r] = -1e30f;
            }
        }

        float pm = s0[0];
        #pragma unroll
        for (int r = 1; r < 16; r++) pm = fmaxf(pm, s0[r]);
        #pragma unroll
        for (int r = 0; r < 16; r++) pm = fmaxf(pm, s1[r]);
        pm = fmaxf(pm, __shfl_xor(pm, 32));
        float pms = pm * SCALE_L2E;
        if (__any(pms - ms > 8.0f)) {
            float msn = fmaxf(ms, pms);
            float alpha = exp2f(ms - msn);
            ms = msn;
            lsum *= alpha;
            #pragma unroll
            for (int r = 0; r < 16; r++) { o0[r] *= alpha; o1[r] *= alpha; }
        }

        float part = 0.f;
        #pragma unroll
        for (int r = 0; r < 16; r++) {
            float p0 = exp2f(s0[r] * SCALE_L2E - ms);
            float p1 = exp2f(s1[r] * SCALE_L2E - ms);
            s0[r] = p0; s1[r] = p1;
            part += p0 + p1;
        }
        lsum += part + __shfl_xor(part, 32);

        unsigned w0[8], w1[8];
        #pragma unroll
        for (int j = 0; j < 8; j++) {
            asm("v_cvt_pk_bf16_f32 %0, %1, %2" : "=v"(w0[j]) : "v"(s0[2 * j]), "v"(s0[2 * j + 1]));
            asm("v_cvt_pk_bf16_f32 %0, %1, %2" : "=v"(w1[j]) : "v"(s1[2 * j]), "v"(s1[2 * j + 1]));
        }

        #define PV_TILE(W, ST)                                                              \
        {                                                                                   \
            _Pragma("unroll")                                                               \
            for (int kkl = 0; kkl < 2; kkl++) {                                             \
                unsigned a  = W[4 * kkl],     bsw = W[4 * kkl + 2];                         \
                unsigned a2 = W[4 * kkl + 1], b2  = W[4 * kkl + 3];                         \
                swap32(a, bsw); swap32(a2, b2);                                             \
                union { int4 i; short8 s; } u;                                              \
                u.i = make_int4((int)a, (int)a2, (int)bsw, (int)b2);                        \
                {                                                                           \
                    int row = l31;                                                          \
                    short8 va = *(const short8*)(Vt + row * 128                             \
                                  + (((ST) * 64 + kkl * 32 + hA * 16) ^ swz(row)));         \
                    o0 = __builtin_amdgcn_mfma_f32_32x32x16_bf16(va, u.s, o0, 0, 0, 0);     \
                }                                                                           \
                {                                                                           \
                    int row = 32 + l31;                                                     \
                    short8 va = *(const short8*)(Vt + row * 128                             \
                                  + (((ST) * 64 + kkl * 32 + hA * 16) ^ swz(row)));         \
                    o1 = __builtin_amdgcn_mfma_f32_32x32x16_bf16(va, u.s, o1, 0, 0, 0);     \
                }                                                                           \
            }                                                                               \
        }
        PV_TILE(w0, 0)
        PV_TILE(w1, 1)
        #undef PV_TILE
    }

    // ---- epilogue: normalize, transpose O^T -> O via LDS, store bf16 ----
    __syncthreads();   // all tiles done reading K/V buffers
    float rinv = 1.0f / lsum;
    char* Ot = alds + wave * 4096;     // 32 rows x 64 d per wave (4KB), wave-private
    const int X = (l31 & 7) << 4;
    #pragma unroll
    for (int rq = 0; rq < 4; rq++) {
        u16x4 pk0, pk1;
        #pragma unroll
        for (int j = 0; j < 4; j++) {
            pk0[j] = f2bf(o0[4 * rq + j] * rinv);    // d = 8*rq + 4*hA + j
            pk1[j] = f2bf(o1[4 * rq + j] * rinv);    // d = 32 + 8*rq + 4*hA + j
        }
        *(u16x4*)(Ot + l31 * 128 + ((16 * rq + 8 * hA) ^ X))      = pk0;
        *(u16x4*)(Ot + l31 * 128 + ((64 + 16 * rq + 8 * hA) ^ X)) = pk1;
    }
    __syncthreads();
    #pragma unroll
    for (int p = 0; p < 4; p++) {
        int row = p * 8 + (lane >> 3);               // 0..31 within wave's tile
        int cc  = lane & 7;                          // 16B chunk (8 d-elems)
        short8 vv = *(const short8*)(Ot + row * 128 + ((cc * 16) ^ ((row & 7) << 4)));
        *(short8*)(y + (rowbase + q0 + wave * 32 + row) * E + h * 64 + cc * 8) = vv;
    }
}

// ---------------- launch ----------------
extern "C" void kernel_launch(void* const* d_in, const int* in_sizes, int n_in,
                              void* d_out, int out_size, void* d_ws, size_t ws_size,
                              hipStream_t stream) {
    const float* x     = (const float*)d_in[0];   // [8,1024,1024]
    const float* Wattn = (const float*)d_in[1];   // [1024,3072]
    const float* Wproj = (const float*)d_in[2];   // [1024,1024]
    float* out = (float*)d_out;                   // [8,1024,1024] fp32

    char* ws = (char*)d_ws;
    u16* buf0 = (u16*)ws;                                  // x_bf16, later y_bf16 (16.78 MB)
    u16* wT   = (u16*)(ws + 16777216);                     // W^T bf16 (6.29 MB, reused)
    u16* qkv  = (u16*)(ws + 16777216 + 6291456);           // [8192][3072] bf16 (50.3 MB)

    // x -> bf16
    k_conv_x<<<2048, 256, 0, stream>>>(x, buf0, 8388608 / 4);
    // W_attn^T -> bf16 [3072][1024]
    k_transpose_bf<<<dim3(3072 / 32, 1024 / 32), dim3(32, 8), 0, stream>>>(Wattn, wT, 1024, 3072);
    // qkv = x @ W_attn   (bf16 out): 256x256, grid 12x32 = 384 wgs
    k_gemmL<true><<<dim3(3072 / 256, 8192 / 256), 512, 0, stream>>>(buf0, wT, qkv, 3072, 1024);
    // W_proj^T -> bf16 [1024][1024]
    k_transpose_bf<<<dim3(1024 / 32, 1024 / 32), dim3(32, 8), 0, stream>>>(Wproj, wT, 1024, 1024);
    // flash attention -> y (reuses buf0)
    k_attn<<<dim3(1024), 256, 0, stream>>>(qkv, buf0);
    // out = y @ W_proj  (fp32 out): 256x256, grid 4x32 = 128 wgs
    k_gemmL<false><<<dim3(1024 / 256, 8192 / 256), 512, 0, stream>>>(buf0, wT, out, 1024, 1024);
}

// Round 13
// 140.045 us; speedup vs baseline: 1.0716x; 1.0716x over previous
//
#include <hip/hip_runtime.h>
#include <hip/hip_bf16.h>

typedef unsigned short u16;
typedef __attribute__((ext_vector_type(8))) short short8;
typedef __attribute__((ext_vector_type(4))) float f32x4;
typedef __attribute__((ext_vector_type(16))) float f32x16;
typedef __attribute__((ext_vector_type(4))) unsigned short u16x4;

#define DEVINL __device__ __forceinline__

DEVINL u16 f2bf(float f) {
    union { float f; unsigned u; } x; x.f = f;
    unsigned u = x.u;
    u += 0x7fffu + ((u >> 16) & 1u);   // round-to-nearest-even
    return (u16)(u >> 16);
}

DEVINL void gload_lds16(const void* g, void* l) {
    __builtin_amdgcn_global_load_lds(
        (const __attribute__((address_space(1))) unsigned*)g,
        (__attribute__((address_space(3))) unsigned*)l, 16, 0, 0);
}

// XOR swizzle for 128B-stride LDS rows: spreads 16B slots across banks.
DEVINL int swz(int row) { return (((row & 7) ^ ((row >> 3) & 7)) << 4); }

// v_permlane32_swap: after call, for lane<32: a=own a, b=partner's a;
// for lane>=32: a=partner's b, b=own b.
DEVINL void swap32(unsigned& a, unsigned& b) {
#if __has_builtin(__builtin_amdgcn_permlane32_swap)
    typedef __attribute__((ext_vector_type(2))) unsigned uv2;
    uv2 r = __builtin_amdgcn_permlane32_swap(a, b, false, false);
    a = r.x; b = r.y;
#else
    int h = ((int)(threadIdx.x & 63)) >> 5;
    unsigned pa = (unsigned)__shfl_xor((int)a, 32);
    unsigned pb = (unsigned)__shfl_xor((int)b, 32);
    unsigned na = h ? pb : a;
    unsigned nb = h ? b : pa;
    a = na; b = nb;
#endif
}

// ---------------- convert x (fp32 -> bf16), vectorized ----------------
__global__ void k_conv_x(const float* __restrict__ in, u16* __restrict__ out, int n4) {
    int i = blockIdx.x * blockDim.x + threadIdx.x;
    int stride = gridDim.x * blockDim.x;
    for (; i < n4; i += stride) {
        float4 v = ((const float4*)in)[i];
        u16x4 o;
        o.x = f2bf(v.x); o.y = f2bf(v.y); o.z = f2bf(v.z); o.w = f2bf(v.w);
        ((u16x4*)out)[i] = o;
    }
}

// ---------------- transpose + convert: in [R][C] fp32 -> out [C][R] bf16 ----------------
__global__ void k_transpose_bf(const float* __restrict__ in, u16* __restrict__ out, int R, int C) {
    __shared__ float t[32][33];
    int c0 = blockIdx.x * 32, r0 = blockIdx.y * 32;
    int tx = threadIdx.x, ty = threadIdx.y;
    #pragma unroll
    for (int j = 0; j < 32; j += 8)
        t[ty + j][tx] = in[(size_t)(r0 + ty + j) * C + c0 + tx];
    __syncthreads();
    #pragma unroll
    for (int j = 0; j < 32; j += 8)
        out[(size_t)(c0 + ty + j) * R + r0 + tx] = f2bf(t[tx][ty + j]);
}

// ---------------- GEMM-W: 128x256, BK=32, 4 waves, 2 blocks/CU, R8-style loop --------
// C[M][N] = A[M][K] @ BT[N][K]^T, bf16 in, bf16 out. Per-wave 128x64 ->
// LDS-read bytes/FLOP 25% below R8's 64x64. 48KB dbuf -> 2 blocks/CU (co-resident
// overlap, the R8-proven requirement). BK=32 64B-row bank hazard fixed by R10's
// pair-interleaved layout (HW-verified 0 conflicts):
//   byte(r, slot) = (r>>6)*4096 + ((r>>1)&31)*128 + (r&1)*64 + ((slot ^ ((r>>1)&3))<<4)
// Stage: linear gload dest + source-slot permute (both-sides rule).
__global__ __launch_bounds__(256, 2)
void k_gemmW(const u16* __restrict__ A, const u16* __restrict__ BT,
             u16* __restrict__ C, int N, int K) {
    __shared__ char lds[2 * 24576];    // per buf: A @0 (8KB, 128 rows), B @8192 (16KB, 256 rows)

    const int tid  = threadIdx.x;
    const int lane = tid & 63;
    const int lo   = lane & 15;
    const int hi   = lane >> 4;
    const int wn   = tid >> 6;         // wave 0..3 -> 64-col band

    // XCD-aware bijective block swizzle (nwg % 8 == 0)
    const int gx   = gridDim.x;
    const int nwg  = gx * gridDim.y;
    const int orig = blockIdx.y * gx + blockIdx.x;
    const int wg   = (orig & 7) * (nwg >> 3) + (orig >> 3);
    const long row0 = (long)(wg / gx) * 128;
    const long col0 = (long)(wg % gx) * 256;

    const int NT = K >> 5;             // BK = 32

    // staging: 4KB chunk = 64 rows; thread -> row 2*(tid>>3)+((tid>>2)&1),
    // global k-slot (tid&3) ^ ((tid>>3)&3); dest linear tid*16.
    const int srow = 2 * (tid >> 3) + ((tid >> 2) & 1);     // 0..63
    const int ssb  = ((tid & 3) ^ ((tid >> 3) & 3)) << 4;   // source slot byte

    auto stage = [&](int t) {
        char* base = lds + (t & 1) * 24576;
        #pragma unroll
        for (int c = 0; c < 2; c++)      // A: 128 rows = 2 chunks
            gload_lds16((const char*)(A + (row0 + c * 64 + srow) * (size_t)K + t * 32) + ssb,
                        base + c * 4096 + tid * 16);
        #pragma unroll
        for (int c = 0; c < 4; c++)      // B: 256 rows = 4 chunks
            gload_lds16((const char*)(BT + (col0 + c * 64 + srow) * (size_t)K + t * 32) + ssb,
                        base + 8192 + c * 4096 + tid * 16);
    };

    f32x4 acc[8][4] = {};

    stage(0);
    asm volatile("s_waitcnt vmcnt(0)" ::: "memory");
    __builtin_amdgcn_s_barrier();

    for (int t = 0; t < NT; t++) {
        if (t + 1 < NT) stage(t + 1);               // issue early: hides under MFMA
        const char* ab = lds + (t & 1) * 24576;
        const char* bb = ab + 8192;
        short8 af[8], bf[4];
        #pragma unroll
        for (int m = 0; m < 8; m++) {
            int r = m * 16 + lo;                    // 0..127
            af[m] = *(const short8*)(ab + (r >> 6) * 4096 + ((r >> 1) & 31) * 128
                                        + (r & 1) * 64 + ((hi ^ ((r >> 1) & 3)) << 4));
        }
        #pragma unroll
        for (int n = 0; n < 4; n++) {
            int r = wn * 64 + n * 16 + lo;          // 0..255
            bf[n] = *(const short8*)(bb + (r >> 6) * 4096 + ((r >> 1) & 31) * 128
                                        + (r & 1) * 64 + ((hi ^ ((r >> 1) & 3)) << 4));
        }
        #pragma unroll
        for (int m = 0; m < 8; m++)
            #pragma unroll
            for (int n = 0; n < 4; n++)
                acc[m][n] = __builtin_amdgcn_mfma_f32_16x16x32_bf16(af[m], bf[n], acc[m][n], 0, 0, 0);
        if (t + 1 < NT) {
            asm volatile("s_waitcnt vmcnt(0)" ::: "memory");   // t+1 resident
            __builtin_amdgcn_s_barrier();                      // all reads of buf[t] done
        }
    }

    // ---- epilogue (bf16 out) ----
    #pragma unroll
    for (int m = 0; m < 8; m++)
        #pragma unroll
        for (int n = 0; n < 4; n++)
            #pragma unroll
            for (int r = 0; r < 4; r++) {
                long row = row0 + m * 16 + hi * 4 + r;
                long col = col0 + wn * 64 + n * 16 + lo;
                C[row * (size_t)N + col] = f2bf(acc[m][n][r]);
            }
}

// ---------------- GEMM: 128x128, BK=64, 2-phase pipeline (R8 proven) — for GEMM2 ------
template<bool OUT_BF16>
__global__ __launch_bounds__(256, 2)
void k_gemm2(const u16* __restrict__ A, const u16* __restrict__ BT,
             void* __restrict__ C, int N, int K) {
    __shared__ char lds[2 * 32768];    // per buf: A @0 (16KB), B @16384 (16KB)

    const int tid  = threadIdx.x;
    const int lane = tid & 63;
    const int lo   = lane & 15;
    const int hi   = lane >> 4;
    const int wave = tid >> 6;
    const int wm   = wave >> 1;
    const int wn   = wave & 1;

    const int gx   = gridDim.x;
    const int nwg  = gx * gridDim.y;
    const int orig = blockIdx.y * gx + blockIdx.x;
    const int wg   = (orig & 7) * (nwg >> 3) + (orig >> 3);
    const long row0 = (long)(wg / gx) * 128;
    const long col0 = (long)(wg % gx) * 128;

    const int NT = K >> 6;             // BK = 64

    const int srow = tid >> 3;                         // 0..31 (row within 32-row chunk)
    const int gsb  = ((tid & 7) ^ (srow & 7)) << 4;    // pre-swizzled source byte

    auto stage = [&](int t) {
        char* base = lds + (t & 1) * 32768;
        #pragma unroll
        for (int c = 0; c < 4; c++)
            gload_lds16((const char*)(A + (row0 + c * 32 + srow) * (size_t)K + t * 64) + gsb,
                        base + c * 4096 + tid * 16);
        #pragma unroll
        for (int c = 0; c < 4; c++)
            gload_lds16((const char*)(BT + (col0 + c * 32 + srow) * (size_t)K + t * 64) + gsb,
                        base + 16384 + c * 4096 + tid * 16);
    };

    f32x4 acc[4][4] = {};

    stage(0);
    asm volatile("s_waitcnt vmcnt(0)" ::: "memory");
    __builtin_amdgcn_s_barrier();

    for (int t = 0; t < NT; t++) {
        if (t + 1 < NT) stage(t + 1);               // issue early: hides under MFMA
        const char* ab = lds + (t & 1) * 32768;
        const char* bb = ab + 16384;
        #pragma unroll
        for (int kk = 0; kk < 2; kk++) {
            short8 af[4], bf[4];
            #pragma unroll
            for (int m = 0; m < 4; m++) {
                int r = wm * 64 + m * 16 + lo;
                af[m] = *(const short8*)(ab + r * 128 + ((kk * 64 + hi * 16) ^ ((r & 7) << 4)));
            }
            #pragma unroll
            for (int n = 0; n < 4; n++) {
                int r = wn * 64 + n * 16 + lo;
                bf[n] = *(const short8*)(bb + r * 128 + ((kk * 64 + hi * 16) ^ ((r & 7) << 4)));
            }
            #pragma unroll
            for (int m = 0; m < 4; m++)
                #pragma unroll
                for (int n = 0; n < 4; n++)
                    acc[m][n] = __builtin_amdgcn_mfma_f32_16x16x32_bf16(af[m], bf[n], acc[m][n], 0, 0, 0);
        }
        if (t + 1 < NT) {
            asm volatile("s_waitcnt vmcnt(0)" ::: "memory");   // t+1 resident
            __builtin_amdgcn_s_barrier();                      // all reads of buf[t] done
        }
    }

    #pragma unroll
    for (int m = 0; m < 4; m++)
        #pragma unroll
        for (int n = 0; n < 4; n++)
            #pragma unroll
            for (int r = 0; r < 4; r++) {
                long row = row0 + wm * 64 + m * 16 + hi * 4 + r;
                long col = col0 + wn * 64 + n * 16 + lo;
                if constexpr (OUT_BF16)
                    ((u16*)C)[row * (size_t)N + col] = f2bf(acc[m][n][r]);
                else
                    ((float*)C)[row * (size_t)N + col] = acc[m][n][r];
            }
}

// ---------------- Flash attention v4: swapped-operand 32x32 + double-buffered K/V ------
// grid: 1024 blocks (8 qi x 128 bh), longest-first. Block = 4 waves x 32 q-rows = 128 q.
#define SCALE_L2E 0.18033688011112042f  // (1/sqrt(64)) * log2(e)

__global__ __launch_bounds__(256, 2)
void k_attn(const u16* __restrict__ qkv, u16* __restrict__ y) {
    constexpr int S = 1024, E = 1024, TE = 3072;
    __shared__ char alds[2 * 16384];   // per buf: K @0 (8KB, [kv][d] swz), V @8192 ([d][kv] swz)

    const int tid  = threadIdx.x;
    const int lane = tid & 63;
    const int l31  = lane & 31;
    const int hA   = lane >> 5;
    const int wave = tid >> 6;

    const int qi = 7 - (int)(blockIdx.x >> 7);   // longest first
    const int bh = blockIdx.x & 127;
    const int b  = bh >> 4;
    const int h  = bh & 15;
    const int q0 = qi * 128;
    const size_t rowbase = (size_t)b * S;
    const int qg = q0 + wave * 32 + l31;         // this lane's q-row

    short8 qf[4];
    {
        const u16* qp = qkv + (rowbase + qg) * TE + h * 64 + hA * 8;
        #pragma unroll
        for (int kd = 0; kd < 4; kd++) qf[kd] = *(const short8*)(qp + kd * 16);
    }

    f32x16 o0 = {}, o1 = {};
    float ms = -1e30f, lsum = 0.f;

    const int kr0 = (wave << 3) + (lane >> 3);
    const int kcb = (lane & 7) * 16;
    const int vkv = (tid >> 3) * 2;
    const int vdc = (tid & 7) * 8;

    auto stage = [&](int t) {
        char* base = alds + (t & 1) * 16384;
        const int kv0 = t * 64;
        #pragma unroll
        for (int it = 0; it < 2; it++) {
            int r = kr0 + it * 32;
            const char* src = (const char*)qkv
                + (((rowbase + kv0 + r) * TE + E + h * 64) << 1) + (kcb ^ swz(r));
            gload_lds16(src, base + wave * 1024 + it * 4096);
        }
        const u16* vsrc = qkv + (rowbase + kv0 + vkv) * TE + 2 * E + h * 64 + vdc;
        short8 v0 = *(const short8*)vsrc;
        short8 v1 = *(const short8*)(vsrc + TE);
        #pragma unroll
        for (int j = 0; j < 8; j++) {
            int d = vdc + j;
            unsigned val = (unsigned)(u16)v0[j] | ((unsigned)(u16)v1[j] << 16);
            *(unsigned*)(base + 8192 + d * 128 + ((vkv * 2) ^ swz(d))) = val;
        }
    };

    const int ntiles = 2 * qi + 2;
    stage(0);
    for (int t = 0; t < ntiles; ++t) {
        __syncthreads();                       // buf[t] resident; prior reads done
        if (t + 1 < ntiles) stage(t + 1);      // overlaps with compute(t)

        const char* Kt = alds + (t & 1) * 16384;
        const char* Vt = Kt + 8192;
        const int kv0 = t * 64;

        const bool active = (kv0 <= q0 + wave * 32 + 31);
        if (!active) continue;   // wave-uniform; still hits next iter's barrier

        f32x16 s0 = {}, s1 = {};
        #pragma unroll
        for (int kd = 0; kd < 4; kd++) {
            int r0 = l31, r1 = 32 + l31;
            short8 ka0 = *(const short8*)(Kt + r0 * 128 + ((kd * 32 + hA * 16) ^ swz(r0)));
            short8 ka1 = *(const short8*)(Kt + r1 * 128 + ((kd * 32 + hA * 16) ^ swz(r1)));
            s0 = __builtin_amdgcn_mfma_f32_32x32x16_bf16(ka0, qf[kd], s0, 0, 0, 0);
            s1 = __builtin_amdgcn_mfma_f32_32x32x16_bf16(ka1, qf[kd], s1, 0, 0, 0);
        }

        if (kv0 + 63 > q0 + wave * 32) {
            #pragma unroll
            for (int r = 0; r < 16; r++) {
                int kvr = kv0 + ((r & 3) + 8 * (r >> 2) + 4 * hA);
                if (kvr > qg)      s0[r] = -1e30f;
                if (kvr + 32 > qg) s1[r] = -1e30f;
            }
        }

        float pm = s0[0];
        #pragma unroll
        for (int r = 1; r < 16; r++) pm = fmaxf(pm, s0[r]);
        #pragma unroll
        for (int r = 0; r < 16; r++) pm = fmaxf(pm, s1[r]);
        pm = fmaxf(pm, __shfl_xor(pm, 32));
        float pms = pm * SCALE_L2E;
        if (__any(pms - ms > 8.0f)) {
            float msn = fmaxf(ms, pms);
            float alpha = exp2f(ms - msn);
            ms = msn;
            lsum *= alpha;
            #pragma unroll
            for (int r = 0; r < 16; r++) { o0[r] *= alpha; o1[r] *= alpha; }
        }

        float part = 0.f;
        #pragma unroll
        for (int r = 0; r < 16; r++) {
            float p0 = exp2f(s0[r] * SCALE_L2E - ms);
            float p1 = exp2f(s1[r] * SCALE_L2E - ms);
            s0[r] = p0; s1[r] = p1;
            part += p0 + p1;
        }
        lsum += part + __shfl_xor(part, 32);

        unsigned w0[8], w1[8];
        #pragma unroll
        for (int j = 0; j < 8; j++) {
            asm("v_cvt_pk_bf16_f32 %0, %1, %2" : "=v"(w0[j]) : "v"(s0[2 * j]), "v"(s0[2 * j + 1]));
            asm("v_cvt_pk_bf16_f32 %0, %1, %2" : "=v"(w1[j]) : "v"(s1[2 * j]), "v"(s1[2 * j + 1]));
        }

        #define PV_TILE(W, ST)                                                              \
        {                                                                                   \
            _Pragma("unroll")                                                               \
            for (int kkl = 0; kkl < 2; kkl++) {                                             \
                unsigned a  = W[4 * kkl],     bsw = W[4 * kkl + 2];                         \
                unsigned a2 = W[4 * kkl + 1], b2  = W[4 * kkl + 3];                         \
                swap32(a, bsw); swap32(a2, b2);                                             \
                union { int4 i; short8 s; } u;                                              \
                u.i = make_int4((int)a, (int)a2, (int)bsw, (int)b2);                        \
                {                                                                           \
                    int row = l31;                                                          \
                    short8 va = *(const short8*)(Vt + row * 128                             \
                                  + (((ST) * 64 + kkl * 32 + hA * 16) ^ swz(row)));         \
                    o0 = __builtin_amdgcn_mfma_f32_32x32x16_bf16(va, u.s, o0, 0, 0, 0);     \
                }                                                                           \
                {                                                                           \
                    int row = 32 + l31;                                                     \
                    short8 va = *(const short8*)(Vt + row * 128                             \
                                  + (((ST) * 64 + kkl * 32 + hA * 16) ^ swz(row)));         \
                    o1 = __builtin_amdgcn_mfma_f32_32x32x16_bf16(va, u.s, o1, 0, 0, 0);     \
                }                                                                           \
            }                                                                               \
        }
        PV_TILE(w0, 0)
        PV_TILE(w1, 1)
        #undef PV_TILE
    }

    // ---- epilogue: normalize, transpose O^T -> O via LDS, store bf16 ----
    __syncthreads();   // all tiles done reading K/V buffers
    float rinv = 1.0f / lsum;
    char* Ot = alds + wave * 4096;     // 32 rows x 64 d per wave (4KB), wave-private
    const int X = (l31 & 7) << 4;
    #pragma unroll
    for (int rq = 0; rq < 4; rq++) {
        u16x4 pk0, pk1;
        #pragma unroll
        for (int j = 0; j < 4; j++) {
            pk0[j] = f2bf(o0[4 * rq + j] * rinv);    // d = 8*rq + 4*hA + j
            pk1[j] = f2bf(o1[4 * rq + j] * rinv);    // d = 32 + 8*rq + 4*hA + j
        }
        *(u16x4*)(Ot + l31 * 128 + ((16 * rq + 8 * hA) ^ X))      = pk0;
        *(u16x4*)(Ot + l31 * 128 + ((64 + 16 * rq + 8 * hA) ^ X)) = pk1;
    }
    __syncthreads();
    #pragma unroll
    for (int p = 0; p < 4; p++) {
        int row = p * 8 + (lane >> 3);               // 0..31 within wave's tile
        int cc  = lane & 7;                          // 16B chunk (8 d-elems)
        short8 vv = *(const short8*)(Ot + row * 128 + ((cc * 16) ^ ((row & 7) << 4)));
        *(short8*)(y + (rowbase + q0 + wave * 32 + row) * E + h * 64 + cc * 8) = vv;
    }
}

// ---------------- launch ----------------
extern "C" void kernel_launch(void* const* d_in, const int* in_sizes, int n_in,
                              void* d_out, int out_size, void* d_ws, size_t ws_size,
                              hipStream_t stream) {
    const float* x     = (const float*)d_in[0];   // [8,1024,1024]
    const float* Wattn = (const float*)d_in[1];   // [1024,3072]
    const float* Wproj = (const float*)d_in[2];   // [1024,1024]
    float* out = (float*)d_out;                   // [8,1024,1024] fp32

    char* ws = (char*)d_ws;
    u16* buf0 = (u16*)ws;                                  // x_bf16, later y_bf16 (16.78 MB)
    u16* wT   = (u16*)(ws + 16777216);                     // W^T bf16 (6.29 MB, reused)
    u16* qkv  = (u16*)(ws + 16777216 + 6291456);           // [8192][3072] bf16 (50.3 MB)

    // x -> bf16
    k_conv_x<<<2048, 256, 0, stream>>>(x, buf0, 8388608 / 4);
    // W_attn^T -> bf16 [3072][1024]
    k_transpose_bf<<<dim3(3072 / 32, 1024 / 32), dim3(32, 8), 0, stream>>>(Wattn, wT, 1024, 3072);
    // qkv = x @ W_attn   (bf16 out): 128x256 BK=32, 2 blocks/CU, grid 12x64 = 768 wgs
    k_gemmW<<<dim3(3072 / 256, 8192 / 128), 256, 0, stream>>>(buf0, wT, qkv, 3072, 1024);
    // W_proj^T -> bf16 [1024][1024]
    k_transpose_bf<<<dim3(1024 / 32, 1024 / 32), dim3(32, 8), 0, stream>>>(Wproj, wT, 1024, 1024);
    // flash attention -> y (reuses buf0)
    k_attn<<<dim3(1024), 256, 0, stream>>>(qkv, buf0);
    // out = y @ W_proj  (fp32 out): 128x128 2-phase, grid 8x64 = 512 wgs
    k_gemm2<false><<<dim3(1024 / 128, 8192 / 128), 256, 0, stream>>>(buf0, wT, out, 1024, 1024);
}

// Round 14
// 132.170 us; speedup vs baseline: 1.1354x; 1.0596x over previous
//
#include <hip/hip_runtime.h>
#include <hip/hip_bf16.h>

typedef unsigned short u16;
typedef __attribute__((ext_vector_type(8))) short short8;
typedef __attribute__((ext_vector_type(4))) float f32x4;
typedef __attribute__((ext_vector_type(16))) float f32x16;
typedef __attribute__((ext_vector_type(4))) unsigned short u16x4;

#define DEVINL __device__ __forceinline__

DEVINL u16 f2bf(float f) {
    union { float f; unsigned u; } x; x.f = f;
    unsigned u = x.u;
    u += 0x7fffu + ((u >> 16) & 1u);   // round-to-nearest-even
    return (u16)(u >> 16);
}

DEVINL void gload_lds16(const void* g, void* l) {
    __builtin_amdgcn_global_load_lds(
        (const __attribute__((address_space(1))) unsigned*)g,
        (__attribute__((address_space(3))) unsigned*)l, 16, 0, 0);
}

// XOR swizzle for 128B-stride LDS rows: spreads 16B slots across banks.
DEVINL int swz(int row) { return (((row & 7) ^ ((row >> 3) & 7)) << 4); }

// v_permlane32_swap: after call, for lane<32: a=own a, b=partner's a;
// for lane>=32: a=partner's b, b=own b.
DEVINL void swap32(unsigned& a, unsigned& b) {
#if __has_builtin(__builtin_amdgcn_permlane32_swap)
    typedef __attribute__((ext_vector_type(2))) unsigned uv2;
    uv2 r = __builtin_amdgcn_permlane32_swap(a, b, false, false);
    a = r.x; b = r.y;
#else
    int h = ((int)(threadIdx.x & 63)) >> 5;
    unsigned pa = (unsigned)__shfl_xor((int)a, 32);
    unsigned pb = (unsigned)__shfl_xor((int)b, 32);
    unsigned na = h ? pb : a;
    unsigned nb = h ? b : pa;
    a = na; b = nb;
#endif
}

// ---------------- fused prep: x->bf16 (blocks 0..2047) + W_attn^T (blocks 2048..5119) ----
__global__ __launch_bounds__(256)
void k_prep(const float* __restrict__ x, const float* __restrict__ Wa,
            u16* __restrict__ xb, u16* __restrict__ waT) {
    __shared__ float t[32][33];
    const int blk = blockIdx.x;
    const int tid = threadIdx.x;
    if (blk < 2048) {
        int i = blk * 256 + tid;
        const int stride = 2048 * 256;
        #pragma unroll
        for (int it = 0; it < 4; it++, i += stride) {   // 2097152 float4s
            float4 v = ((const float4*)x)[i];
            u16x4 o;
            o.x = f2bf(v.x); o.y = f2bf(v.y); o.z = f2bf(v.z); o.w = f2bf(v.w);
            ((u16x4*)xb)[i] = o;
        }
    } else {
        const int b  = blk - 2048;          // W_attn [1024][3072] -> waT [3072][1024]
        const int bx = b % 96, by = b / 96; // 96 x 32 blocks
        const int c0 = bx * 32, r0 = by * 32;
        const int tx = tid & 31, ty = tid >> 5;
        #pragma unroll
        for (int j = 0; j < 32; j += 8)
            t[ty + j][tx] = x /*dummy*/ == nullptr ? 0.f : Wa[(size_t)(r0 + ty + j) * 3072 + c0 + tx];
        __syncthreads();
        #pragma unroll
        for (int j = 0; j < 32; j += 8)
            waT[(size_t)(c0 + ty + j) * 1024 + r0 + tx] = f2bf(t[tx][ty + j]);
    }
}

// ---------------- transpose + convert: in [R][C] fp32 -> out [C][R] bf16 ----------------
__global__ void k_transpose_bf(const float* __restrict__ in, u16* __restrict__ out, int R, int C) {
    __shared__ float t[32][33];
    int c0 = blockIdx.x * 32, r0 = blockIdx.y * 32;
    int tx = threadIdx.x, ty = threadIdx.y;
    #pragma unroll
    for (int j = 0; j < 32; j += 8)
        t[ty + j][tx] = in[(size_t)(r0 + ty + j) * C + c0 + tx];
    __syncthreads();
    #pragma unroll
    for (int j = 0; j < 32; j += 8)
        out[(size_t)(c0 + ty + j) * R + r0 + tx] = f2bf(t[tx][ty + j]);
}

// ---------------- GEMM: 128x128, BK=64, 2-phase pipeline (R8) + drain-hiding split ------
// C[M][N] = A[M][K] @ BT[N][K]^T, bf16 in, bf16/f32 out.
// 4 waves (2x2), per-wave 64x64. Double-buffered LDS (2 x 32KB -> 2 blocks/CU).
// Per K-step: stage(t+1) first; ALL 16 frag reads; 16 MFMA (kk=0); vmcnt(0)+barrier;
// 16 MFMA (kk=1, registers only -> legally execute past the barrier, giving the
// matrix pipe work while the next step's ds_reads are in flight).
template<bool OUT_BF16>
__global__ __launch_bounds__(256, 2)
void k_gemm2(const u16* __restrict__ A, const u16* __restrict__ BT,
             void* __restrict__ C, int N, int K) {
    __shared__ char lds[2 * 32768];    // per buf: A @0 (16KB), B @16384 (16KB)

    const int tid  = threadIdx.x;
    const int lane = tid & 63;
    const int lo   = lane & 15;
    const int hi   = lane >> 4;
    const int wave = tid >> 6;
    const int wm   = wave >> 1;
    const int wn   = wave & 1;

    // XCD-aware bijective block swizzle (nwg % 8 == 0 for our grids)
    const int gx   = gridDim.x;
    const int nwg  = gx * gridDim.y;
    const int orig = blockIdx.y * gx + blockIdx.x;
    const int wg   = (orig & 7) * (nwg >> 3) + (orig >> 3);
    const long row0 = (long)(wg / gx) * 128;
    const long col0 = (long)(wg % gx) * 128;

    const int NT = K >> 6;             // BK = 64

    const int srow = tid >> 3;                         // 0..31 (row within 32-row chunk)
    const int gsb  = ((tid & 7) ^ (srow & 7)) << 4;    // pre-swizzled source byte

    auto stage = [&](int t) {
        char* base = lds + (t & 1) * 32768;
        #pragma unroll
        for (int c = 0; c < 4; c++)
            gload_lds16((const char*)(A + (row0 + c * 32 + srow) * (size_t)K + t * 64) + gsb,
                        base + c * 4096 + tid * 16);
        #pragma unroll
        for (int c = 0; c < 4; c++)
            gload_lds16((const char*)(BT + (col0 + c * 32 + srow) * (size_t)K + t * 64) + gsb,
                        base + 16384 + c * 4096 + tid * 16);
    };

    f32x4 acc[4][4] = {};

    stage(0);
    asm volatile("s_waitcnt vmcnt(0)" ::: "memory");
    __builtin_amdgcn_s_barrier();

    for (int t = 0; t < NT; t++) {
        if (t + 1 < NT) stage(t + 1);               // issue early: hides under MFMA
        const char* ab = lds + (t & 1) * 32768;
        const char* bb = ab + 16384;
        short8 af[2][4], bf[2][4];
        #pragma unroll
        for (int kk = 0; kk < 2; kk++) {
            #pragma unroll
            for (int m = 0; m < 4; m++) {
                int r = wm * 64 + m * 16 + lo;
                af[kk][m] = *(const short8*)(ab + r * 128 + ((kk * 64 + hi * 16) ^ ((r & 7) << 4)));
            }
            #pragma unroll
            for (int n = 0; n < 4; n++) {
                int r = wn * 64 + n * 16 + lo;
                bf[kk][n] = *(const short8*)(bb + r * 128 + ((kk * 64 + hi * 16) ^ ((r & 7) << 4)));
            }
        }
        #pragma unroll
        for (int m = 0; m < 4; m++)
            #pragma unroll
            for (int n = 0; n < 4; n++)
                acc[m][n] = __builtin_amdgcn_mfma_f32_16x16x32_bf16(af[0][m], bf[0][n], acc[m][n], 0, 0, 0);
        if (t + 1 < NT) {
            asm volatile("s_waitcnt vmcnt(0)" ::: "memory");   // t+1 resident
            __builtin_amdgcn_s_barrier();                      // all reads of buf[t] done
        }
        #pragma unroll
        for (int m = 0; m < 4; m++)
            #pragma unroll
            for (int n = 0; n < 4; n++)
                acc[m][n] = __builtin_amdgcn_mfma_f32_16x16x32_bf16(af[1][m], bf[1][n], acc[m][n], 0, 0, 0);
    }

    // ---- epilogue ----
    #pragma unroll
    for (int m = 0; m < 4; m++)
        #pragma unroll
        for (int n = 0; n < 4; n++)
            #pragma unroll
            for (int r = 0; r < 4; r++) {
                long row = row0 + wm * 64 + m * 16 + hi * 4 + r;
                long col = col0 + wn * 64 + n * 16 + lo;
                if constexpr (OUT_BF16)
                    ((u16*)C)[row * (size_t)N + col] = f2bf(acc[m][n][r]);
                else
                    ((float*)C)[row * (size_t)N + col] = acc[m][n][r];
            }
}

// ---------------- Flash attention v4: swapped-operand 32x32 + double-buffered K/V ------
// grid: 1024 blocks (8 qi x 128 bh), longest-first. Block = 4 waves x 32 q-rows = 128 q.
#define SCALE_L2E 0.18033688011112042f  // (1/sqrt(64)) * log2(e)

__global__ __launch_bounds__(256, 2)
void k_attn(const u16* __restrict__ qkv, u16* __restrict__ y) {
    constexpr int S = 1024, E = 1024, TE = 3072;
    __shared__ char alds[2 * 16384];   // per buf: K @0 (8KB, [kv][d] swz), V @8192 ([d][kv] swz)

    const int tid  = threadIdx.x;
    const int lane = tid & 63;
    const int l31  = lane & 31;
    const int hA   = lane >> 5;
    const int wave = tid >> 6;

    const int qi = 7 - (int)(blockIdx.x >> 7);   // longest first
    const int bh = blockIdx.x & 127;
    const int b  = bh >> 4;
    const int h  = bh & 15;
    const int q0 = qi * 128;
    const size_t rowbase = (size_t)b * S;
    const int qg = q0 + wave * 32 + l31;         // this lane's q-row

    short8 qf[4];
    {
        const u16* qp = qkv + (rowbase + qg) * TE + h * 64 + hA * 8;
        #pragma unroll
        for (int kd = 0; kd < 4; kd++) qf[kd] = *(const short8*)(qp + kd * 16);
    }

    f32x16 o0 = {}, o1 = {};
    float ms = -1e30f, lsum = 0.f;

    const int kr0 = (wave << 3) + (lane >> 3);
    const int kcb = (lane & 7) * 16;
    const int vkv = (tid >> 3) * 2;
    const int vdc = (tid & 7) * 8;

    auto stage = [&](int t) {
        char* base = alds + (t & 1) * 16384;
        const int kv0 = t * 64;
        #pragma unroll
        for (int it = 0; it < 2; it++) {
            int r = kr0 + it * 32;
            const char* src = (const char*)qkv
                + (((rowbase + kv0 + r) * TE + E + h * 64) << 1) + (kcb ^ swz(r));
            gload_lds16(src, base + wave * 1024 + it * 4096);
        }
        const u16* vsrc = qkv + (rowbase + kv0 + vkv) * TE + 2 * E + h * 64 + vdc;
        short8 v0 = *(const short8*)vsrc;
        short8 v1 = *(const short8*)(vsrc + TE);
        #pragma unroll
        for (int j = 0; j < 8; j++) {
            int d = vdc + j;
            unsigned val = (unsigned)(u16)v0[j] | ((unsigned)(u16)v1[j] << 16);
            *(unsigned*)(base + 8192 + d * 128 + ((vkv * 2) ^ swz(d))) = val;
        }
    };

    const int ntiles = 2 * qi + 2;
    stage(0);
    for (int t = 0; t < ntiles; ++t) {
        __syncthreads();                       // buf[t] resident; prior reads done
        if (t + 1 < ntiles) stage(t + 1);      // overlaps with compute(t)

        const char* Kt = alds + (t & 1) * 16384;
        const char* Vt = Kt + 8192;
        const int kv0 = t * 64;

        const bool active = (kv0 <= q0 + wave * 32 + 31);
        if (!active) continue;   // wave-uniform; still hits next iter's barrier

        f32x16 s0 = {}, s1 = {};
        #pragma unroll
        for (int kd = 0; kd < 4; kd++) {
            int r0 = l31, r1 = 32 + l31;
            short8 ka0 = *(const short8*)(Kt + r0 * 128 + ((kd * 32 + hA * 16) ^ swz(r0)));
            short8 ka1 = *(const short8*)(Kt + r1 * 128 + ((kd * 32 + hA * 16) ^ swz(r1)));
            s0 = __builtin_amdgcn_mfma_f32_32x32x16_bf16(ka0, qf[kd], s0, 0, 0, 0);
            s1 = __builtin_amdgcn_mfma_f32_32x32x16_bf16(ka1, qf[kd], s1, 0, 0, 0);
        }

        if (kv0 + 63 > q0 + wave * 32) {
            #pragma unroll
            for (int r = 0; r < 16; r++) {
                int kvr = kv0 + ((r & 3) + 8 * (r >> 2) + 4 * hA);
                if (kvr > qg)      s0[r] = -1e30f;
                if (kvr + 32 > qg) s1[r] = -1e30f;
            }
        }

        float pm = s0[0];
        #pragma unroll
        for (int r = 1; r < 16; r++) pm = fmaxf(pm, s0[r]);
        #pragma unroll
        for (int r = 0; r < 16; r++) pm = fmaxf(pm, s1[r]);
        pm = fmaxf(pm, __shfl_xor(pm, 32));
        float pms = pm * SCALE_L2E;
        if (__any(pms - ms > 8.0f)) {
            float msn = fmaxf(ms, pms);
            float alpha = exp2f(ms - msn);
            ms = msn;
            lsum *= alpha;
            #pragma unroll
            for (int r = 0; r < 16; r++) { o0[r] *= alpha; o1[r] *= alpha; }
        }

        float part = 0.f;
        #pragma unroll
        for (int r = 0; r < 16; r++) {
            float p0 = exp2f(s0[r] * SCALE_L2E - ms);
            float p1 = exp2f(s1[r] * SCALE_L2E - ms);
            s0[r] = p0; s1[r] = p1;
            part += p0 + p1;
        }
        lsum += part + __shfl_xor(part, 32);

        unsigned w0[8], w1[8];
        #pragma unroll
        for (int j = 0; j < 8; j++) {
            asm("v_cvt_pk_bf16_f32 %0, %1, %2" : "=v"(w0[j]) : "v"(s0[2 * j]), "v"(s0[2 * j + 1]));
            asm("v_cvt_pk_bf16_f32 %0, %1, %2" : "=v"(w1[j]) : "v"(s1[2 * j]), "v"(s1[2 * j + 1]));
        }

        #define PV_TILE(W, ST)                                                              \
        {                                                                                   \
            _Pragma("unroll")                                                               \
            for (int kkl = 0; kkl < 2; kkl++) {                                             \
                unsigned a  = W[4 * kkl],     bsw = W[4 * kkl + 2];                         \
                unsigned a2 = W[4 * kkl + 1], b2  = W[4 * kkl + 3];                         \
                swap32(a, bsw); swap32(a2, b2);                                             \
                union { int4 i; short8 s; } u;                                              \
                u.i = make_int4((int)a, (int)a2, (int)bsw, (int)b2);                        \
                {                                                                           \
                    int row = l31;                                                          \
                    short8 va = *(const short8*)(Vt + row * 128                             \
                                  + (((ST) * 64 + kkl * 32 + hA * 16) ^ swz(row)));         \
                    o0 = __builtin_amdgcn_mfma_f32_32x32x16_bf16(va, u.s, o0, 0, 0, 0);     \
                }                                                                           \
                {                                                                           \
                    int row = 32 + l31;                                                     \
                    short8 va = *(const short8*)(Vt + row * 128                             \
                                  + (((ST) * 64 + kkl * 32 + hA * 16) ^ swz(row)));         \
                    o1 = __builtin_amdgcn_mfma_f32_32x32x16_bf16(va, u.s, o1, 0, 0, 0);     \
                }                                                                           \
            }                                                                               \
        }
        PV_TILE(w0, 0)
        PV_TILE(w1, 1)
        #undef PV_TILE
    }

    // ---- epilogue: normalize, transpose O^T -> O via LDS, store bf16 ----
    __syncthreads();   // all tiles done reading K/V buffers
    float rinv = 1.0f / lsum;
    char* Ot = alds + wave * 4096;     // 32 rows x 64 d per wave (4KB), wave-private
    const int X = (l31 & 7) << 4;
    #pragma unroll
    for (int rq = 0; rq < 4; rq++) {
        u16x4 pk0, pk1;
        #pragma unroll
        for (int j = 0; j < 4; j++) {
            pk0[j] = f2bf(o0[4 * rq + j] * rinv);    // d = 8*rq + 4*hA + j
            pk1[j] = f2bf(o1[4 * rq + j] * rinv);    // d = 32 + 8*rq + 4*hA + j
        }
        *(u16x4*)(Ot + l31 * 128 + ((16 * rq + 8 * hA) ^ X))      = pk0;
        *(u16x4*)(Ot + l31 * 128 + ((64 + 16 * rq + 8 * hA) ^ X)) = pk1;
    }
    __syncthreads();
    #pragma unroll
    for (int p = 0; p < 4; p++) {
        int row = p * 8 + (lane >> 3);               // 0..31 within wave's tile
        int cc  = lane & 7;                          // 16B chunk (8 d-elems)
        short8 vv = *(const short8*)(Ot + row * 128 + ((cc * 16) ^ ((row & 7) << 4)));
        *(short8*)(y + (rowbase + q0 + wave * 32 + row) * E + h * 64 + cc * 8) = vv;
    }
}

// ---------------- launch ----------------
extern "C" void kernel_launch(void* const* d_in, const int* in_sizes, int n_in,
                              void* d_out, int out_size, void* d_ws, size_t ws_size,
                              hipStream_t stream) {
    const float* x     = (const float*)d_in[0];   // [8,1024,1024]
    const float* Wattn = (const float*)d_in[1];   // [1024,3072]
    const float* Wproj = (const float*)d_in[2];   // [1024,1024]
    float* out = (float*)d_out;                   // [8,1024,1024] fp32

    char* ws = (char*)d_ws;
    u16* buf0 = (u16*)ws;                                  // x_bf16, later y_bf16 (16.78 MB)
    u16* wT   = (u16*)(ws + 16777216);                     // W^T bf16 (6.29 MB, reused)
    u16* qkv  = (u16*)(ws + 16777216 + 6291456);           // [8192][3072] bf16 (50.3 MB)

    // fused: x -> bf16 (blocks 0..2047) + W_attn^T (blocks 2048..5119)
    k_prep<<<5120, 256, 0, stream>>>(x, Wattn, buf0, wT);
    // qkv = x @ W_attn   (bf16 out): 128x128 2-phase, grid 24x64 = 1536 wgs
    k_gemm2<true><<<dim3(3072 / 128, 8192 / 128), 256, 0, stream>>>(buf0, wT, qkv, 3072, 1024);
    // W_proj^T -> bf16 [1024][1024] (overwrites wT; GEMM1 done in stream order)
    k_transpose_bf<<<dim3(1024 / 32, 1024 / 32), dim3(32, 8), 0, stream>>>(Wproj, wT, 1024, 1024);
    // flash attention -> y (reuses buf0)
    k_attn<<<dim3(1024), 256, 0, stream>>>(qkv, buf0);
    // out = y @ W_proj  (fp32 out): 128x128 2-phase, grid 8x64 = 512 wgs
    k_gemm2<false><<<dim3(1024 / 128, 8192 / 128), 256, 0, stream>>>(buf0, wT, out, 1024, 1024);
}

// Round 15
// 128.877 us; speedup vs baseline: 1.1644x; 1.0256x over previous
//
#include <hip/hip_runtime.h>
#include <hip/hip_bf16.h>

typedef unsigned short u16;
typedef __attribute__((ext_vector_type(8))) short short8;
typedef __attribute__((ext_vector_type(4))) float f32x4;
typedef __attribute__((ext_vector_type(16))) float f32x16;
typedef __attribute__((ext_vector_type(4))) unsigned short u16x4;

#define DEVINL __device__ __forceinline__

DEVINL u16 f2bf(float f) {
    union { float f; unsigned u; } x; x.f = f;
    unsigned u = x.u;
    u += 0x7fffu + ((u >> 16) & 1u);   // round-to-nearest-even
    return (u16)(u >> 16);
}

DEVINL void gload_lds16(const void* g, void* l) {
    __builtin_amdgcn_global_load_lds(
        (const __attribute__((address_space(1))) unsigned*)g,
        (__attribute__((address_space(3))) unsigned*)l, 16, 0, 0);
}

// XOR swizzle for 128B-stride LDS rows: spreads 16B slots across banks.
DEVINL int swz(int row) { return (((row & 7) ^ ((row >> 3) & 7)) << 4); }

// v_permlane32_swap: after call, for lane<32: a=own a, b=partner's a;
// for lane>=32: a=partner's b, b=own b.
DEVINL void swap32(unsigned& a, unsigned& b) {
#if __has_builtin(__builtin_amdgcn_permlane32_swap)
    typedef __attribute__((ext_vector_type(2))) unsigned uv2;
    uv2 r = __builtin_amdgcn_permlane32_swap(a, b, false, false);
    a = r.x; b = r.y;
#else
    int h = ((int)(threadIdx.x & 63)) >> 5;
    unsigned pa = (unsigned)__shfl_xor((int)a, 32);
    unsigned pb = (unsigned)__shfl_xor((int)b, 32);
    unsigned na = h ? pb : a;
    unsigned nb = h ? b : pa;
    a = na; b = nb;
#endif
}

// ---------------- fused prep ----------------
// blocks 0..2047:    x fp32 -> bf16 (grid-stride float4)
// blocks 2048..5119: W_attn [1024][3072] -> waT [3072][1024] bf16
// blocks 5120..6143: W_proj [1024][1024] -> wpT [1024][1024] bf16 (only if grid=6144)
__global__ __launch_bounds__(256)
void k_prep(const float* __restrict__ x, const float* __restrict__ Wa,
            const float* __restrict__ Wp,
            u16* __restrict__ xb, u16* __restrict__ waT, u16* __restrict__ wpT) {
    __shared__ float t[32][33];
    const int blk = blockIdx.x;
    const int tid = threadIdx.x;
    if (blk < 2048) {
        int i = blk * 256 + tid;
        const int stride = 2048 * 256;
        #pragma unroll
        for (int it = 0; it < 4; it++, i += stride) {   // 2097152 float4s
            float4 v = ((const float4*)x)[i];
            u16x4 o;
            o.x = f2bf(v.x); o.y = f2bf(v.y); o.z = f2bf(v.z); o.w = f2bf(v.w);
            ((u16x4*)xb)[i] = o;
        }
    } else if (blk < 5120) {
        const int b  = blk - 2048;          // 96 x 32 blocks
        const int bx = b % 96, by = b / 96;
        const int c0 = bx * 32, r0 = by * 32;
        const int tx = tid & 31, ty = tid >> 5;
        #pragma unroll
        for (int j = 0; j < 32; j += 8)
            t[ty + j][tx] = Wa[(size_t)(r0 + ty + j) * 3072 + c0 + tx];
        __syncthreads();
        #pragma unroll
        for (int j = 0; j < 32; j += 8)
            waT[(size_t)(c0 + ty + j) * 1024 + r0 + tx] = f2bf(t[tx][ty + j]);
    } else {
        const int b  = blk - 5120;          // 32 x 32 blocks
        const int bx = b & 31, by = b >> 5;
        const int c0 = bx * 32, r0 = by * 32;
        const int tx = tid & 31, ty = tid >> 5;
        #pragma unroll
        for (int j = 0; j < 32; j += 8)
            t[ty + j][tx] = Wp[(size_t)(r0 + ty + j) * 1024 + c0 + tx];
        __syncthreads();
        #pragma unroll
        for (int j = 0; j < 32; j += 8)
            wpT[(size_t)(c0 + ty + j) * 1024 + r0 + tx] = f2bf(t[tx][ty + j]);
    }
}

// ---------------- transpose + convert (fallback path only) ----------------
__global__ void k_transpose_bf(const float* __restrict__ in, u16* __restrict__ out, int R, int C) {
    __shared__ float t[32][33];
    int c0 = blockIdx.x * 32, r0 = blockIdx.y * 32;
    int tx = threadIdx.x, ty = threadIdx.y;
    #pragma unroll
    for (int j = 0; j < 32; j += 8)
        t[ty + j][tx] = in[(size_t)(r0 + ty + j) * C + c0 + tx];
    __syncthreads();
    #pragma unroll
    for (int j = 0; j < 32; j += 8)
        out[(size_t)(c0 + ty + j) * R + r0 + tx] = f2bf(t[tx][ty + j]);
}

// ---------------- GEMM: 128x128, BK=64, 2-phase pipeline (R8) + kk-split ----------------
// C[M][N] = A[M][K] @ BT[N][K]^T, bf16 in, bf16/f32 out.
// 4 waves (2x2), per-wave 64x64. Double-buffered LDS (2 x 32KB -> 2 blocks/CU).
// Per K-step: stage(t+1) first; ALL 16 frag reads; 16 MFMA (kk=0); vmcnt(0)+barrier;
// 16 MFMA (kk=1, registers only -> execute past the barrier, feeding the matrix pipe
// while the next step's ds_reads are in flight).
template<bool OUT_BF16>
__global__ __launch_bounds__(256, 2)
void k_gemm2(const u16* __restrict__ A, const u16* __restrict__ BT,
             void* __restrict__ C, int N, int K) {
    __shared__ char lds[2 * 32768];    // per buf: A @0 (16KB), B @16384 (16KB)

    const int tid  = threadIdx.x;
    const int lane = tid & 63;
    const int lo   = lane & 15;
    const int hi   = lane >> 4;
    const int wave = tid >> 6;
    const int wm   = wave >> 1;
    const int wn   = wave & 1;

    // XCD-aware bijective block swizzle (nwg % 8 == 0 for our grids)
    const int gx   = gridDim.x;
    const int nwg  = gx * gridDim.y;
    const int orig = blockIdx.y * gx + blockIdx.x;
    const int wg   = (orig & 7) * (nwg >> 3) + (orig >> 3);
    const long row0 = (long)(wg / gx) * 128;
    const long col0 = (long)(wg % gx) * 128;

    const int NT = K >> 6;             // BK = 64

    const int srow = tid >> 3;                         // 0..31 (row within 32-row chunk)
    const int gsb  = ((tid & 7) ^ (srow & 7)) << 4;    // pre-swizzled source byte

    auto stage = [&](int t) {
        char* base = lds + (t & 1) * 32768;
        #pragma unroll
        for (int c = 0; c < 4; c++)
            gload_lds16((const char*)(A + (row0 + c * 32 + srow) * (size_t)K + t * 64) + gsb,
                        base + c * 4096 + tid * 16);
        #pragma unroll
        for (int c = 0; c < 4; c++)
            gload_lds16((const char*)(BT + (col0 + c * 32 + srow) * (size_t)K + t * 64) + gsb,
                        base + 16384 + c * 4096 + tid * 16);
    };

    f32x4 acc[4][4] = {};

    stage(0);
    asm volatile("s_waitcnt vmcnt(0)" ::: "memory");
    __builtin_amdgcn_s_barrier();

    for (int t = 0; t < NT; t++) {
        if (t + 1 < NT) stage(t + 1);               // issue early: hides under MFMA
        const char* ab = lds + (t & 1) * 32768;
        const char* bb = ab + 16384;
        short8 af[2][4], bf[2][4];
        #pragma unroll
        for (int kk = 0; kk < 2; kk++) {
            #pragma unroll
            for (int m = 0; m < 4; m++) {
                int r = wm * 64 + m * 16 + lo;
                af[kk][m] = *(const short8*)(ab + r * 128 + ((kk * 64 + hi * 16) ^ ((r & 7) << 4)));
            }
            #pragma unroll
            for (int n = 0; n < 4; n++) {
                int r = wn * 64 + n * 16 + lo;
                bf[kk][n] = *(const short8*)(bb + r * 128 + ((kk * 64 + hi * 16) ^ ((r & 7) << 4)));
            }
        }
        #pragma unroll
        for (int m = 0; m < 4; m++)
            #pragma unroll
            for (int n = 0; n < 4; n++)
                acc[m][n] = __builtin_amdgcn_mfma_f32_16x16x32_bf16(af[0][m], bf[0][n], acc[m][n], 0, 0, 0);
        if (t + 1 < NT) {
            asm volatile("s_waitcnt vmcnt(0)" ::: "memory");   // t+1 resident
            __builtin_amdgcn_s_barrier();                      // all reads of buf[t] done
        }
        #pragma unroll
        for (int m = 0; m < 4; m++)
            #pragma unroll
            for (int n = 0; n < 4; n++)
                acc[m][n] = __builtin_amdgcn_mfma_f32_16x16x32_bf16(af[1][m], bf[1][n], acc[m][n], 0, 0, 0);
    }

    // ---- epilogue ----
    #pragma unroll
    for (int m = 0; m < 4; m++)
        #pragma unroll
        for (int n = 0; n < 4; n++)
            #pragma unroll
            for (int r = 0; r < 4; r++) {
                long row = row0 + wm * 64 + m * 16 + hi * 4 + r;
                long col = col0 + wn * 64 + n * 16 + lo;
                if constexpr (OUT_BF16)
                    ((u16*)C)[row * (size_t)N + col] = f2bf(acc[m][n][r]);
                else
                    ((float*)C)[row * (size_t)N + col] = acc[m][n][r];
            }
}

// ---------------- Flash attention v4: swapped-operand 32x32 + double-buffered K/V ------
// grid: 1024 blocks (8 qi x 128 bh), longest-first. Block = 4 waves x 32 q-rows = 128 q.
#define SCALE_L2E 0.18033688011112042f  // (1/sqrt(64)) * log2(e)

__global__ __launch_bounds__(256, 2)
void k_attn(const u16* __restrict__ qkv, u16* __restrict__ y) {
    constexpr int S = 1024, E = 1024, TE = 3072;
    __shared__ char alds[2 * 16384];   // per buf: K @0 (8KB, [kv][d] swz), V @8192 ([d][kv] swz)

    const int tid  = threadIdx.x;
    const int lane = tid & 63;
    const int l31  = lane & 31;
    const int hA   = lane >> 5;
    const int wave = tid >> 6;

    const int qi = 7 - (int)(blockIdx.x >> 7);   // longest first
    const int bh = blockIdx.x & 127;
    const int b  = bh >> 4;
    const int h  = bh & 15;
    const int q0 = qi * 128;
    const size_t rowbase = (size_t)b * S;
    const int qg = q0 + wave * 32 + l31;         // this lane's q-row

    short8 qf[4];
    {
        const u16* qp = qkv + (rowbase + qg) * TE + h * 64 + hA * 8;
        #pragma unroll
        for (int kd = 0; kd < 4; kd++) qf[kd] = *(const short8*)(qp + kd * 16);
    }

    f32x16 o0 = {}, o1 = {};
    float ms = -1e30f, lsum = 0.f;

    const int kr0 = (wave << 3) + (lane >> 3);
    const int kcb = (lane & 7) * 16;
    const int vkv = (tid >> 3) * 2;
    const int vdc = (tid & 7) * 8;

    auto stage = [&](int t) {
        char* base = alds + (t & 1) * 16384;
        const int kv0 = t * 64;
        #pragma unroll
        for (int it = 0; it < 2; it++) {
            int r = kr0 + it * 32;
            const char* src = (const char*)qkv
                + (((rowbase + kv0 + r) * TE + E + h * 64) << 1) + (kcb ^ swz(r));
            gload_lds16(src, base + wave * 1024 + it * 4096);
        }
        const u16* vsrc = qkv + (rowbase + kv0 + vkv) * TE + 2 * E + h * 64 + vdc;
        short8 v0 = *(const short8*)vsrc;
        short8 v1 = *(const short8*)(vsrc + TE);
        #pragma unroll
        for (int j = 0; j < 8; j++) {
            int d = vdc + j;
            unsigned val = (unsigned)(u16)v0[j] | ((unsigned)(u16)v1[j] << 16);
            *(unsigned*)(base + 8192 + d * 128 + ((vkv * 2) ^ swz(d))) = val;
        }
    };

    const int ntiles = 2 * qi + 2;
    stage(0);
    for (int t = 0; t < ntiles; ++t) {
        __syncthreads();                       // buf[t] resident; prior reads done
        if (t + 1 < ntiles) stage(t + 1);      // overlaps with compute(t)

        const char* Kt = alds + (t & 1) * 16384;
        const char* Vt = Kt + 8192;
        const int kv0 = t * 64;

        const bool active = (kv0 <= q0 + wave * 32 + 31);
        if (!active) continue;   // wave-uniform; still hits next iter's barrier

        f32x16 s0 = {}, s1 = {};
        #pragma unroll
        for (int kd = 0; kd < 4; kd++) {
            int r0 = l31, r1 = 32 + l31;
            short8 ka0 = *(const short8*)(Kt + r0 * 128 + ((kd * 32 + hA * 16) ^ swz(r0)));
            short8 ka1 = *(const short8*)(Kt + r1 * 128 + ((kd * 32 + hA * 16) ^ swz(r1)));
            s0 = __builtin_amdgcn_mfma_f32_32x32x16_bf16(ka0, qf[kd], s0, 0, 0, 0);
            s1 = __builtin_amdgcn_mfma_f32_32x32x16_bf16(ka1, qf[kd], s1, 0, 0, 0);
        }

        if (kv0 + 63 > q0 + wave * 32) {
            #pragma unroll
            for (int r = 0; r < 16; r++) {
                int kvr = kv0 + ((r & 3) + 8 * (r >> 2) + 4 * hA);
                if (kvr > qg)      s0[r] = -1e30f;
                if (kvr + 32 > qg) s1[r] = -1e30f;
            }
        }

        float pm = s0[0];
        #pragma unroll
        for (int r = 1; r < 16; r++) pm = fmaxf(pm, s0[r]);
        #pragma unroll
        for (int r = 0; r < 16; r++) pm = fmaxf(pm, s1[r]);
        pm = fmaxf(pm, __shfl_xor(pm, 32));
        float pms = pm * SCALE_L2E;
        if (__any(pms - ms > 8.0f)) {
            float msn = fmaxf(ms, pms);
            float alpha = exp2f(ms - msn);
            ms = msn;
            lsum *= alpha;
            #pragma unroll
            for (int r = 0; r < 16; r++) { o0[r] *= alpha; o1[r] *= alpha; }
        }

        float part = 0.f;
        #pragma unroll
        for (int r = 0; r < 16; r++) {
            float p0 = exp2f(s0[r] * SCALE_L2E - ms);
            float p1 = exp2f(s1[r] * SCALE_L2E - ms);
            s0[r] = p0; s1[r] = p1;
            part += p0 + p1;
        }
        lsum += part + __shfl_xor(part, 32);

        unsigned w0[8], w1[8];
        #pragma unroll
        for (int j = 0; j < 8; j++) {
            asm("v_cvt_pk_bf16_f32 %0, %1, %2" : "=v"(w0[j]) : "v"(s0[2 * j]), "v"(s0[2 * j + 1]));
            asm("v_cvt_pk_bf16_f32 %0, %1, %2" : "=v"(w1[j]) : "v"(s1[2 * j]), "v"(s1[2 * j + 1]));
        }

        #define PV_TILE(W, ST)                                                              \
        {                                                                                   \
            _Pragma("unroll")                                                               \
            for (int kkl = 0; kkl < 2; kkl++) {                                             \
                unsigned a  = W[4 * kkl],     bsw = W[4 * kkl + 2];                         \
                unsigned a2 = W[4 * kkl + 1], b2  = W[4 * kkl + 3];                         \
                swap32(a, bsw); swap32(a2, b2);                                             \
                union { int4 i; short8 s; } u;                                              \
                u.i = make_int4((int)a, (int)a2, (int)bsw, (int)b2);                        \
                {                                                                           \
                    int row = l31;                                                          \
                    short8 va = *(const short8*)(Vt + row * 128                             \
                                  + (((ST) * 64 + kkl * 32 + hA * 16) ^ swz(row)));         \
                    o0 = __builtin_amdgcn_mfma_f32_32x32x16_bf16(va, u.s, o0, 0, 0, 0);     \
                }                                                                           \
                {                                                                           \
                    int row = 32 + l31;                                                     \
                    short8 va = *(const short8*)(Vt + row * 128                             \
                                  + (((ST) * 64 + kkl * 32 + hA * 16) ^ swz(row)));         \
                    o1 = __builtin_amdgcn_mfma_f32_32x32x16_bf16(va, u.s, o1, 0, 0, 0);     \
                }                                                                           \
            }                                                                               \
        }
        PV_TILE(w0, 0)
        PV_TILE(w1, 1)
        #undef PV_TILE
    }

    // ---- epilogue: normalize, transpose O^T -> O via LDS, store bf16 ----
    __syncthreads();   // all tiles done reading K/V buffers
    float rinv = 1.0f / lsum;
    char* Ot = alds + wave * 4096;     // 32 rows x 64 d per wave (4KB), wave-private
    const int X = (l31 & 7) << 4;
    #pragma unroll
    for (int rq = 0; rq < 4; rq++) {
        u16x4 pk0, pk1;
        #pragma unroll
        for (int j = 0; j < 4; j++) {
            pk0[j] = f2bf(o0[4 * rq + j] * rinv);    // d = 8*rq + 4*hA + j
            pk1[j] = f2bf(o1[4 * rq + j] * rinv);    // d = 32 + 8*rq + 4*hA + j
        }
        *(u16x4*)(Ot + l31 * 128 + ((16 * rq + 8 * hA) ^ X))      = pk0;
        *(u16x4*)(Ot + l31 * 128 + ((64 + 16 * rq + 8 * hA) ^ X)) = pk1;
    }
    __syncthreads();
    #pragma unroll
    for (int p = 0; p < 4; p++) {
        int row = p * 8 + (lane >> 3);               // 0..31 within wave's tile
        int cc  = lane & 7;                          // 16B chunk (8 d-elems)
        short8 vv = *(const short8*)(Ot + row * 128 + ((cc * 16) ^ ((row & 7) << 4)));
        *(short8*)(y + (rowbase + q0 + wave * 32 + row) * E + h * 64 + cc * 8) = vv;
    }
}

// ---------------- launch ----------------
extern "C" void kernel_launch(void* const* d_in, const int* in_sizes, int n_in,
                              void* d_out, int out_size, void* d_ws, size_t ws_size,
                              hipStream_t stream) {
    const float* x     = (const float*)d_in[0];   // [8,1024,1024]
    const float* Wattn = (const float*)d_in[1];   // [1024,3072]
    const float* Wproj = (const float*)d_in[2];   // [1024,1024]
    float* out = (float*)d_out;                   // [8,1024,1024] fp32

    char* ws = (char*)d_ws;
    u16* buf0 = (u16*)ws;                                  // x_bf16, later y_bf16 (16.78 MB)
    u16* wT   = (u16*)(ws + 16777216);                     // W_attn^T bf16 (6.29 MB)
    u16* qkv  = (u16*)(ws + 16777216 + 6291456);           // [8192][3072] bf16 (50.3 MB)
    const size_t wpT_off = 16777216ull + 6291456 + 50331648;
    const bool fused_wp = ws_size >= wpT_off + 2097152;    // room for W_proj^T?
    u16* wpT  = fused_wp ? (u16*)(ws + wpT_off) : wT;      // fallback: reuse wT

    // fused prep: x->bf16 + W_attn^T (+ W_proj^T when buffer space allows)
    k_prep<<<fused_wp ? 6144 : 5120, 256, 0, stream>>>(x, Wattn, Wproj, buf0, wT, wpT);
    // qkv = x @ W_attn   (bf16 out): 128x128 2-phase, grid 24x64 = 1536 wgs
    k_gemm2<true><<<dim3(3072 / 128, 8192 / 128), 256, 0, stream>>>(buf0, wT, qkv, 3072, 1024);
    if (!fused_wp) {
        // fallback: W_proj^T -> wT after GEMM1 (old R14 path)
        k_transpose_bf<<<dim3(1024 / 32, 1024 / 32), dim3(32, 8), 0, stream>>>(Wproj, wT, 1024, 1024);
    }
    // flash attention -> y (reuses buf0)
    k_attn<<<dim3(1024), 256, 0, stream>>>(qkv, buf0);
    // out = y @ W_proj  (fp32 out): 128x128 2-phase, grid 8x64 = 512 wgs
    k_gemm2<false><<<dim3(1024 / 128, 8192 / 128), 256, 0, stream>>>(buf0, wpT, out, 1024, 1024);
}

// Round 16
// 125.712 us; speedup vs baseline: 1.1938x; 1.0252x over previous
//
#include <hip/hip_runtime.h>
#include <hip/hip_bf16.h>

typedef unsigned short u16;
typedef __attribute__((ext_vector_type(8))) short short8;
typedef __attribute__((ext_vector_type(4))) float f32x4;
typedef __attribute__((ext_vector_type(16))) float f32x16;
typedef __attribute__((ext_vector_type(4))) unsigned short u16x4;

#define DEVINL __device__ __forceinline__

DEVINL u16 f2bf(float f) {
    union { float f; unsigned u; } x; x.f = f;
    unsigned u = x.u;
    u += 0x7fffu + ((u >> 16) & 1u);   // round-to-nearest-even
    return (u16)(u >> 16);
}

DEVINL void gload_lds16(const void* g, void* l) {
    __builtin_amdgcn_global_load_lds(
        (const __attribute__((address_space(1))) unsigned*)g,
        (__attribute__((address_space(3))) unsigned*)l, 16, 0, 0);
}

// XOR swizzle for 128B-stride LDS rows: spreads 16B slots across banks.
DEVINL int swz(int row) { return (((row & 7) ^ ((row >> 3) & 7)) << 4); }

// v_permlane32_swap: after call, for lane<32: a=own a, b=partner's a;
// for lane>=32: a=partner's b, b=own b.
DEVINL void swap32(unsigned& a, unsigned& b) {
#if __has_builtin(__builtin_amdgcn_permlane32_swap)
    typedef __attribute__((ext_vector_type(2))) unsigned uv2;
    uv2 r = __builtin_amdgcn_permlane32_swap(a, b, false, false);
    a = r.x; b = r.y;
#else
    int h = ((int)(threadIdx.x & 63)) >> 5;
    unsigned pa = (unsigned)__shfl_xor((int)a, 32);
    unsigned pb = (unsigned)__shfl_xor((int)b, 32);
    unsigned na = h ? pb : a;
    unsigned nb = h ? b : pa;
    a = na; b = nb;
#endif
}

// ---------------- fused prep ----------------
// blocks 0..2047:    x fp32 -> bf16 (grid-stride float4)
// blocks 2048..5119: W_attn [1024][3072] -> waT [3072][1024] bf16
// blocks 5120..6143: W_proj [1024][1024] -> wpT [1024][1024] bf16 (only if grid=6144)
__global__ __launch_bounds__(256)
void k_prep(const float* __restrict__ x, const float* __restrict__ Wa,
            const float* __restrict__ Wp,
            u16* __restrict__ xb, u16* __restrict__ waT, u16* __restrict__ wpT) {
    __shared__ float t[32][33];
    const int blk = blockIdx.x;
    const int tid = threadIdx.x;
    if (blk < 2048) {
        int i = blk * 256 + tid;
        const int stride = 2048 * 256;
        #pragma unroll
        for (int it = 0; it < 4; it++, i += stride) {   // 2097152 float4s
            float4 v = ((const float4*)x)[i];
            u16x4 o;
            o.x = f2bf(v.x); o.y = f2bf(v.y); o.z = f2bf(v.z); o.w = f2bf(v.w);
            ((u16x4*)xb)[i] = o;
        }
    } else if (blk < 5120) {
        const int b  = blk - 2048;          // 96 x 32 blocks
        const int bx = b % 96, by = b / 96;
        const int c0 = bx * 32, r0 = by * 32;
        const int tx = tid & 31, ty = tid >> 5;
        #pragma unroll
        for (int j = 0; j < 32; j += 8)
            t[ty + j][tx] = Wa[(size_t)(r0 + ty + j) * 3072 + c0 + tx];
        __syncthreads();
        #pragma unroll
        for (int j = 0; j < 32; j += 8)
            waT[(size_t)(c0 + ty + j) * 1024 + r0 + tx] = f2bf(t[tx][ty + j]);
    } else {
        const int b  = blk - 5120;          // 32 x 32 blocks
        const int bx = b & 31, by = b >> 5;
        const int c0 = bx * 32, r0 = by * 32;
        const int tx = tid & 31, ty = tid >> 5;
        #pragma unroll
        for (int j = 0; j < 32; j += 8)
            t[ty + j][tx] = Wp[(size_t)(r0 + ty + j) * 1024 + c0 + tx];
        __syncthreads();
        #pragma unroll
        for (int j = 0; j < 32; j += 8)
            wpT[(size_t)(c0 + ty + j) * 1024 + r0 + tx] = f2bf(t[tx][ty + j]);
    }
}

// ---------------- transpose + convert (fallback path only) ----------------
__global__ void k_transpose_bf(const float* __restrict__ in, u16* __restrict__ out, int R, int C) {
    __shared__ float t[32][33];
    int c0 = blockIdx.x * 32, r0 = blockIdx.y * 32;
    int tx = threadIdx.x, ty = threadIdx.y;
    #pragma unroll
    for (int j = 0; j < 32; j += 8)
        t[ty + j][tx] = in[(size_t)(r0 + ty + j) * C + c0 + tx];
    __syncthreads();
    #pragma unroll
    for (int j = 0; j < 32; j += 8)
        out[(size_t)(c0 + ty + j) * R + r0 + tx] = f2bf(t[tx][ty + j]);
}

// ---------------- GEMM-T: 128x192, BK=64, 2-phase pipeline, 2 blocks/CU ----------------
// C[M][N] = A[M][K] @ BT[N][K]^T, bf16 in, bf16 out. 4 waves (2x2), per-wave 64x96.
// dbuf 2x40KB = 80KB -> 2 blocks/CU = 160KB (full pool). LDS bytes/FLOP 15% below
// R8's 64x64 wave-tile. Same free-running loop: stage(t+1) first, all frag reads,
// kk=0 MFMAs, vmcnt(0)+barrier, kk=1 MFMAs (register-only, run past the barrier).
__global__ __launch_bounds__(256, 2)
void k_gemmT(const u16* __restrict__ A, const u16* __restrict__ BT,
             u16* __restrict__ C, int N, int K) {
    __shared__ char lds[2 * 40960];    // per buf: A @0 (16KB, 128 rows), B @16384 (24KB, 192 rows)

    const int tid  = threadIdx.x;
    const int lane = tid & 63;
    const int lo   = lane & 15;
    const int hi   = lane >> 4;
    const int wave = tid >> 6;
    const int wm   = wave >> 1;        // 0..1 (64-row band)
    const int wn   = wave & 1;         // 0..1 (96-col band)

    // XCD-aware bijective block swizzle (nwg % 8 == 0)
    const int gx   = gridDim.x;
    const int nwg  = gx * gridDim.y;
    const int orig = blockIdx.y * gx + blockIdx.x;
    const int wg   = (orig & 7) * (nwg >> 3) + (orig >> 3);
    const long row0 = (long)(wg / gx) * 128;
    const long col0 = (long)(wg % gx) * 192;

    const int NT = K >> 6;             // BK = 64

    const int srow = tid >> 3;                         // 0..31 (row within 32-row chunk)
    const int gsb  = ((tid & 7) ^ (srow & 7)) << 4;    // pre-swizzled source byte

    auto stage = [&](int t) {
        char* base = lds + (t & 1) * 40960;
        #pragma unroll
        for (int c = 0; c < 4; c++)      // A: 128 rows = 4 chunks
            gload_lds16((const char*)(A + (row0 + c * 32 + srow) * (size_t)K + t * 64) + gsb,
                        base + c * 4096 + tid * 16);
        #pragma unroll
        for (int c = 0; c < 6; c++)      // B: 192 rows = 6 chunks
            gload_lds16((const char*)(BT + (col0 + c * 32 + srow) * (size_t)K + t * 64) + gsb,
                        base + 16384 + c * 4096 + tid * 16);
    };

    f32x4 acc[4][6] = {};

    stage(0);
    asm volatile("s_waitcnt vmcnt(0)" ::: "memory");
    __builtin_amdgcn_s_barrier();

    for (int t = 0; t < NT; t++) {
        if (t + 1 < NT) stage(t + 1);               // issue early: hides under MFMA
        const char* ab = lds + (t & 1) * 40960;
        const char* bb = ab + 16384;
        short8 af[2][4], bf[2][6];
        #pragma unroll
        for (int kk = 0; kk < 2; kk++) {
            #pragma unroll
            for (int m = 0; m < 4; m++) {
                int r = wm * 64 + m * 16 + lo;      // 0..127
                af[kk][m] = *(const short8*)(ab + r * 128 + ((kk * 64 + hi * 16) ^ ((r & 7) << 4)));
            }
            #pragma unroll
            for (int n = 0; n < 6; n++) {
                int r = wn * 96 + n * 16 + lo;      // 0..191
                bf[kk][n] = *(const short8*)(bb + r * 128 + ((kk * 64 + hi * 16) ^ ((r & 7) << 4)));
            }
        }
        #pragma unroll
        for (int m = 0; m < 4; m++)
            #pragma unroll
            for (int n = 0; n < 6; n++)
                acc[m][n] = __builtin_amdgcn_mfma_f32_16x16x32_bf16(af[0][m], bf[0][n], acc[m][n], 0, 0, 0);
        if (t + 1 < NT) {
            asm volatile("s_waitcnt vmcnt(0)" ::: "memory");   // t+1 resident
            __builtin_amdgcn_s_barrier();                      // all reads of buf[t] done
        }
        #pragma unroll
        for (int m = 0; m < 4; m++)
            #pragma unroll
            for (int n = 0; n < 6; n++)
                acc[m][n] = __builtin_amdgcn_mfma_f32_16x16x32_bf16(af[1][m], bf[1][n], acc[m][n], 0, 0, 0);
    }

    // ---- epilogue (bf16 out) ----
    #pragma unroll
    for (int m = 0; m < 4; m++)
        #pragma unroll
        for (int n = 0; n < 6; n++)
            #pragma unroll
            for (int r = 0; r < 4; r++) {
                long row = row0 + wm * 64 + m * 16 + hi * 4 + r;
                long col = col0 + wn * 96 + n * 16 + lo;
                C[row * (size_t)N + col] = f2bf(acc[m][n][r]);
            }
}

// ---------------- GEMM: 128x128, BK=64, 2-phase pipeline (R8) + kk-split ----------------
// Used for GEMM2 (N=1024, 192 doesn't divide). Same mechanism set.
template<bool OUT_BF16>
__global__ __launch_bounds__(256, 2)
void k_gemm2(const u16* __restrict__ A, const u16* __restrict__ BT,
             void* __restrict__ C, int N, int K) {
    __shared__ char lds[2 * 32768];    // per buf: A @0 (16KB), B @16384 (16KB)

    const int tid  = threadIdx.x;
    const int lane = tid & 63;
    const int lo   = lane & 15;
    const int hi   = lane >> 4;
    const int wave = tid >> 6;
    const int wm   = wave >> 1;
    const int wn   = wave & 1;

    const int gx   = gridDim.x;
    const int nwg  = gx * gridDim.y;
    const int orig = blockIdx.y * gx + blockIdx.x;
    const int wg   = (orig & 7) * (nwg >> 3) + (orig >> 3);
    const long row0 = (long)(wg / gx) * 128;
    const long col0 = (long)(wg % gx) * 128;

    const int NT = K >> 6;             // BK = 64

    const int srow = tid >> 3;                         // 0..31 (row within 32-row chunk)
    const int gsb  = ((tid & 7) ^ (srow & 7)) << 4;    // pre-swizzled source byte

    auto stage = [&](int t) {
        char* base = lds + (t & 1) * 32768;
        #pragma unroll
        for (int c = 0; c < 4; c++)
            gload_lds16((const char*)(A + (row0 + c * 32 + srow) * (size_t)K + t * 64) + gsb,
                        base + c * 4096 + tid * 16);
        #pragma unroll
        for (int c = 0; c < 4; c++)
            gload_lds16((const char*)(BT + (col0 + c * 32 + srow) * (size_t)K + t * 64) + gsb,
                        base + 16384 + c * 4096 + tid * 16);
    };

    f32x4 acc[4][4] = {};

    stage(0);
    asm volatile("s_waitcnt vmcnt(0)" ::: "memory");
    __builtin_amdgcn_s_barrier();

    for (int t = 0; t < NT; t++) {
        if (t + 1 < NT) stage(t + 1);               // issue early: hides under MFMA
        const char* ab = lds + (t & 1) * 32768;
        const char* bb = ab + 16384;
        short8 af[2][4], bf[2][4];
        #pragma unroll
        for (int kk = 0; kk < 2; kk++) {
            #pragma unroll
            for (int m = 0; m < 4; m++) {
                int r = wm * 64 + m * 16 + lo;
                af[kk][m] = *(const short8*)(ab + r * 128 + ((kk * 64 + hi * 16) ^ ((r & 7) << 4)));
            }
            #pragma unroll
            for (int n = 0; n < 4; n++) {
                int r = wn * 64 + n * 16 + lo;
                bf[kk][n] = *(const short8*)(bb + r * 128 + ((kk * 64 + hi * 16) ^ ((r & 7) << 4)));
            }
        }
        #pragma unroll
        for (int m = 0; m < 4; m++)
            #pragma unroll
            for (int n = 0; n < 4; n++)
                acc[m][n] = __builtin_amdgcn_mfma_f32_16x16x32_bf16(af[0][m], bf[0][n], acc[m][n], 0, 0, 0);
        if (t + 1 < NT) {
            asm volatile("s_waitcnt vmcnt(0)" ::: "memory");   // t+1 resident
            __builtin_amdgcn_s_barrier();                      // all reads of buf[t] done
        }
        #pragma unroll
        for (int m = 0; m < 4; m++)
            #pragma unroll
            for (int n = 0; n < 4; n++)
                acc[m][n] = __builtin_amdgcn_mfma_f32_16x16x32_bf16(af[1][m], bf[1][n], acc[m][n], 0, 0, 0);
    }

    #pragma unroll
    for (int m = 0; m < 4; m++)
        #pragma unroll
        for (int n = 0; n < 4; n++)
            #pragma unroll
            for (int r = 0; r < 4; r++) {
                long row = row0 + wm * 64 + m * 16 + hi * 4 + r;
                long col = col0 + wn * 64 + n * 16 + lo;
                if constexpr (OUT_BF16)
                    ((u16*)C)[row * (size_t)N + col] = f2bf(acc[m][n][r]);
                else
                    ((float*)C)[row * (size_t)N + col] = acc[m][n][r];
            }
}

// ---------------- Flash attention v4: swapped-operand 32x32 + double-buffered K/V ------
// grid: 1024 blocks (8 qi x 128 bh), longest-first. Block = 4 waves x 32 q-rows = 128 q.
#define SCALE_L2E 0.18033688011112042f  // (1/sqrt(64)) * log2(e)

__global__ __launch_bounds__(256, 2)
void k_attn(const u16* __restrict__ qkv, u16* __restrict__ y) {
    constexpr int S = 1024, E = 1024, TE = 3072;
    __shared__ char alds[2 * 16384];   // per buf: K @0 (8KB, [kv][d] swz), V @8192 ([d][kv] swz)

    const int tid  = threadIdx.x;
    const int lane = tid & 63;
    const int l31  = lane & 31;
    const int hA   = lane >> 5;
    const int wave = tid >> 6;

    const int qi = 7 - (int)(blockIdx.x >> 7);   // longest first
    const int bh = blockIdx.x & 127;
    const int b  = bh >> 4;
    const int h  = bh & 15;
    const int q0 = qi * 128;
    const size_t rowbase = (size_t)b * S;
    const int qg = q0 + wave * 32 + l31;         // this lane's q-row

    short8 qf[4];
    {
        const u16* qp = qkv + (rowbase + qg) * TE + h * 64 + hA * 8;
        #pragma unroll
        for (int kd = 0; kd < 4; kd++) qf[kd] = *(const short8*)(qp + kd * 16);
    }

    f32x16 o0 = {}, o1 = {};
    float ms = -1e30f, lsum = 0.f;

    const int kr0 = (wave << 3) + (lane >> 3);
    const int kcb = (lane & 7) * 16;
    const int vkv = (tid >> 3) * 2;
    const int vdc = (tid & 7) * 8;

    auto stage = [&](int t) {
        char* base = alds + (t & 1) * 16384;
        const int kv0 = t * 64;
        #pragma unroll
        for (int it = 0; it < 2; it++) {
            int r = kr0 + it * 32;
            const char* src = (const char*)qkv
                + (((rowbase + kv0 + r) * TE + E + h * 64) << 1) + (kcb ^ swz(r));
            gload_lds16(src, base + wave * 1024 + it * 4096);
        }
        const u16* vsrc = qkv + (rowbase + kv0 + vkv) * TE + 2 * E + h * 64 + vdc;
        short8 v0 = *(const short8*)vsrc;
        short8 v1 = *(const short8*)(vsrc + TE);
        #pragma unroll
        for (int j = 0; j < 8; j++) {
            int d = vdc + j;
            unsigned val = (unsigned)(u16)v0[j] | ((unsigned)(u16)v1[j] << 16);
            *(unsigned*)(base + 8192 + d * 128 + ((vkv * 2) ^ swz(d))) = val;
        }
    };

    const int ntiles = 2 * qi + 2;
    stage(0);
    for (int t = 0; t < ntiles; ++t) {
        __syncthreads();                       // buf[t] resident; prior reads done
        if (t + 1 < ntiles) stage(t + 1);      // overlaps with compute(t)

        const char* Kt = alds + (t & 1) * 16384;
        const char* Vt = Kt + 8192;
        const int kv0 = t * 64;

        const bool active = (kv0 <= q0 + wave * 32 + 31);
        if (!active) continue;   // wave-uniform; still hits next iter's barrier

        f32x16 s0 = {}, s1 = {};
        #pragma unroll
        for (int kd = 0; kd < 4; kd++) {
            int r0 = l31, r1 = 32 + l31;
            short8 ka0 = *(const short8*)(Kt + r0 * 128 + ((kd * 32 + hA * 16) ^ swz(r0)));
            short8 ka1 = *(const short8*)(Kt + r1 * 128 + ((kd * 32 + hA * 16) ^ swz(r1)));
            s0 = __builtin_amdgcn_mfma_f32_32x32x16_bf16(ka0, qf[kd], s0, 0, 0, 0);
            s1 = __builtin_amdgcn_mfma_f32_32x32x16_bf16(ka1, qf[kd], s1, 0, 0, 0);
        }

        if (kv0 + 63 > q0 + wave * 32) {
            #pragma unroll
            for (int r = 0; r < 16; r++) {
                int kvr = kv0 + ((r & 3) + 8 * (r >> 2) + 4 * hA);
                if (kvr > qg)      s0[r] = -1e30f;
                if (kvr + 32 > qg) s1[r] = -1e30f;
            }
        }

        float pm = s0[0];
        #pragma unroll
        for (int r = 1; r < 16; r++) pm = fmaxf(pm, s0[r]);
        #pragma unroll
        for (int r = 0; r < 16; r++) pm = fmaxf(pm, s1[r]);
        pm = fmaxf(pm, __shfl_xor(pm, 32));
        float pms = pm * SCALE_L2E;
        if (__any(pms - ms > 8.0f)) {
            float msn = fmaxf(ms, pms);
            float alpha = exp2f(ms - msn);
            ms = msn;
            lsum *= alpha;
            #pragma unroll
            for (int r = 0; r < 16; r++) { o0[r] *= alpha; o1[r] *= alpha; }
        }

        float part = 0.f;
        #pragma unroll
        for (int r = 0; r < 16; r++) {
            float p0 = exp2f(s0[r] * SCALE_L2E - ms);
            float p1 = exp2f(s1[r] * SCALE_L2E - ms);
            s0[r] = p0; s1[r] = p1;
            part += p0 + p1;
        }
        lsum += part + __shfl_xor(part, 32);

        unsigned w0[8], w1[8];
        #pragma unroll
        for (int j = 0; j < 8; j++) {
            asm("v_cvt_pk_bf16_f32 %0, %1, %2" : "=v"(w0[j]) : "v"(s0[2 * j]), "v"(s0[2 * j + 1]));
            asm("v_cvt_pk_bf16_f32 %0, %1, %2" : "=v"(w1[j]) : "v"(s1[2 * j]), "v"(s1[2 * j + 1]));
        }

        #define PV_TILE(W, ST)                                                              \
        {                                                                                   \
            _Pragma("unroll")                                                               \
            for (int kkl = 0; kkl < 2; kkl++) {                                             \
                unsigned a  = W[4 * kkl],     bsw = W[4 * kkl + 2];                         \
                unsigned a2 = W[4 * kkl + 1], b2  = W[4 * kkl + 3];                         \
                swap32(a, bsw); swap32(a2, b2);                                             \
                union { int4 i; short8 s; } u;                                              \
                u.i = make_int4((int)a, (int)a2, (int)bsw, (int)b2);                        \
                {                                                                           \
                    int row = l31;                                                          \
                    short8 va = *(const short8*)(Vt + row * 128                             \
                                  + (((ST) * 64 + kkl * 32 + hA * 16) ^ swz(row)));         \
                    o0 = __builtin_amdgcn_mfma_f32_32x32x16_bf16(va, u.s, o0, 0, 0, 0);     \
                }                                                                           \
                {                                                                           \
                    int row = 32 + l31;                                                     \
                    short8 va = *(const short8*)(Vt + row * 128                             \
                                  + (((ST) * 64 + kkl * 32 + hA * 16) ^ swz(row)));         \
                    o1 = __builtin_amdgcn_mfma_f32_32x32x16_bf16(va, u.s, o1, 0, 0, 0);     \
                }                                                                           \
            }                                                                               \
        }
        PV_TILE(w0, 0)
        PV_TILE(w1, 1)
        #undef PV_TILE
    }

    // ---- epilogue: normalize, transpose O^T -> O via LDS, store bf16 ----
    __syncthreads();   // all tiles done reading K/V buffers
    float rinv = 1.0f / lsum;
    char* Ot = alds + wave * 4096;     // 32 rows x 64 d per wave (4KB), wave-private
    const int X = (l31 & 7) << 4;
    #pragma unroll
    for (int rq = 0; rq < 4; rq++) {
        u16x4 pk0, pk1;
        #pragma unroll
        for (int j = 0; j < 4; j++) {
            pk0[j] = f2bf(o0[4 * rq + j] * rinv);    // d = 8*rq + 4*hA + j
            pk1[j] = f2bf(o1[4 * rq + j] * rinv);    // d = 32 + 8*rq + 4*hA + j
        }
        *(u16x4*)(Ot + l31 * 128 + ((16 * rq + 8 * hA) ^ X))      = pk0;
        *(u16x4*)(Ot + l31 * 128 + ((64 + 16 * rq + 8 * hA) ^ X)) = pk1;
    }
    __syncthreads();
    #pragma unroll
    for (int p = 0; p < 4; p++) {
        int row = p * 8 + (lane >> 3);               // 0..31 within wave's tile
        int cc  = lane & 7;                          // 16B chunk (8 d-elems)
        short8 vv = *(const short8*)(Ot + row * 128 + ((cc * 16) ^ ((row & 7) << 4)));
        *(short8*)(y + (rowbase + q0 + wave * 32 + row) * E + h * 64 + cc * 8) = vv;
    }
}

// ---------------- launch ----------------
extern "C" void kernel_launch(void* const* d_in, const int* in_sizes, int n_in,
                              void* d_out, int out_size, void* d_ws, size_t ws_size,
                              hipStream_t stream) {
    const float* x     = (const float*)d_in[0];   // [8,1024,1024]
    const float* Wattn = (const float*)d_in[1];   // [1024,3072]
    const float* Wproj = (const float*)d_in[2];   // [1024,1024]
    float* out = (float*)d_out;                   // [8,1024,1024] fp32

    char* ws = (char*)d_ws;
    u16* buf0 = (u16*)ws;                                  // x_bf16, later y_bf16 (16.78 MB)
    u16* wT   = (u16*)(ws + 16777216);                     // W_attn^T bf16 (6.29 MB)
    u16* qkv  = (u16*)(ws + 16777216 + 6291456);           // [8192][3072] bf16 (50.3 MB)
    const size_t wpT_off = 16777216ull + 6291456 + 50331648;
    const bool fused_wp = ws_size >= wpT_off + 2097152;    // room for W_proj^T?
    u16* wpT  = fused_wp ? (u16*)(ws + wpT_off) : wT;      // fallback: reuse wT

    // fused prep: x->bf16 + W_attn^T (+ W_proj^T when buffer space allows)
    k_prep<<<fused_wp ? 6144 : 5120, 256, 0, stream>>>(x, Wattn, Wproj, buf0, wT, wpT);
    // qkv = x @ W_attn   (bf16 out): 128x192 tile, grid 16x64 = 1024 wgs, 2 rounds exact
    k_gemmT<<<dim3(3072 / 192, 8192 / 128), 256, 0, stream>>>(buf0, wT, qkv, 3072, 1024);
    if (!fused_wp) {
        // fallback: W_proj^T -> wT after GEMM1 (old R14 path)
        k_transpose_bf<<<dim3(1024 / 32, 1024 / 32), dim3(32, 8), 0, stream>>>(Wproj, wT, 1024, 1024);
    }
    // flash attention -> y (reuses buf0)
    k_attn<<<dim3(1024), 256, 0, stream>>>(qkv, buf0);
    // out = y @ W_proj  (fp32 out): 128x128 2-phase, grid 8x64 = 512 wgs
    k_gemm2<false><<<dim3(1024 / 128, 8192 / 128), 256, 0, stream>>>(buf0, wpT, out, 1024, 1024);
}

// Round 17
// 124.406 us; speedup vs baseline: 1.2063x; 1.0105x over previous
//
#include <hip/hip_runtime.h>
#include <hip/hip_bf16.h>

typedef unsigned short u16;
typedef __attribute__((ext_vector_type(8))) short short8;
typedef __attribute__((ext_vector_type(4))) float f32x4;
typedef __attribute__((ext_vector_type(16))) float f32x16;
typedef __attribute__((ext_vector_type(4))) unsigned short u16x4;

#define DEVINL __device__ __forceinline__

DEVINL u16 f2bf(float f) {
    union { float f; unsigned u; } x; x.f = f;
    unsigned u = x.u;
    u += 0x7fffu + ((u >> 16) & 1u);   // round-to-nearest-even
    return (u16)(u >> 16);
}

DEVINL void gload_lds16(const void* g, void* l) {
    __builtin_amdgcn_global_load_lds(
        (const __attribute__((address_space(1))) unsigned*)g,
        (__attribute__((address_space(3))) unsigned*)l, 16, 0, 0);
}

// XOR swizzle for 128B-stride LDS rows: spreads 16B slots across banks.
DEVINL int swz(int row) { return (((row & 7) ^ ((row >> 3) & 7)) << 4); }

// v_permlane32_swap: after call, for lane<32: a=own a, b=partner's a;
// for lane>=32: a=partner's b, b=own b.
DEVINL void swap32(unsigned& a, unsigned& b) {
#if __has_builtin(__builtin_amdgcn_permlane32_swap)
    typedef __attribute__((ext_vector_type(2))) unsigned uv2;
    uv2 r = __builtin_amdgcn_permlane32_swap(a, b, false, false);
    a = r.x; b = r.y;
#else
    int h = ((int)(threadIdx.x & 63)) >> 5;
    unsigned pa = (unsigned)__shfl_xor((int)a, 32);
    unsigned pb = (unsigned)__shfl_xor((int)b, 32);
    unsigned na = h ? pb : a;
    unsigned nb = h ? b : pa;
    a = na; b = nb;
#endif
}

// ---------------- fused prep ----------------
// blocks 0..2047:    x fp32 -> bf16 (grid-stride float4)
// blocks 2048..5119: W_attn [1024][3072] -> waT [3072][1024] bf16
// blocks 5120..6143: W_proj [1024][1024] -> wpT [1024][1024] bf16 (only if grid=6144)
__global__ __launch_bounds__(256)
void k_prep(const float* __restrict__ x, const float* __restrict__ Wa,
            const float* __restrict__ Wp,
            u16* __restrict__ xb, u16* __restrict__ waT, u16* __restrict__ wpT) {
    __shared__ float t[32][33];
    const int blk = blockIdx.x;
    const int tid = threadIdx.x;
    if (blk < 2048) {
        int i = blk * 256 + tid;
        const int stride = 2048 * 256;
        #pragma unroll
        for (int it = 0; it < 4; it++, i += stride) {   // 2097152 float4s
            float4 v = ((const float4*)x)[i];
            u16x4 o;
            o.x = f2bf(v.x); o.y = f2bf(v.y); o.z = f2bf(v.z); o.w = f2bf(v.w);
            ((u16x4*)xb)[i] = o;
        }
    } else if (blk < 5120) {
        const int b  = blk - 2048;          // 96 x 32 blocks
        const int bx = b % 96, by = b / 96;
        const int c0 = bx * 32, r0 = by * 32;
        const int tx = tid & 31, ty = tid >> 5;
        #pragma unroll
        for (int j = 0; j < 32; j += 8)
            t[ty + j][tx] = Wa[(size_t)(r0 + ty + j) * 3072 + c0 + tx];
        __syncthreads();
        #pragma unroll
        for (int j = 0; j < 32; j += 8)
            waT[(size_t)(c0 + ty + j) * 1024 + r0 + tx] = f2bf(t[tx][ty + j]);
    } else {
        const int b  = blk - 5120;          // 32 x 32 blocks
        const int bx = b & 31, by = b >> 5;
        const int c0 = bx * 32, r0 = by * 32;
        const int tx = tid & 31, ty = tid >> 5;
        #pragma unroll
        for (int j = 0; j < 32; j += 8)
            t[ty + j][tx] = Wp[(size_t)(r0 + ty + j) * 1024 + c0 + tx];
        __syncthreads();
        #pragma unroll
        for (int j = 0; j < 32; j += 8)
            wpT[(size_t)(c0 + ty + j) * 1024 + r0 + tx] = f2bf(t[tx][ty + j]);
    }
}

// ---------------- transpose + convert (fallback path only) ----------------
__global__ void k_transpose_bf(const float* __restrict__ in, u16* __restrict__ out, int R, int C) {
    __shared__ float t[32][33];
    int c0 = blockIdx.x * 32, r0 = blockIdx.y * 32;
    int tx = threadIdx.x, ty = threadIdx.y;
    #pragma unroll
    for (int j = 0; j < 32; j += 8)
        t[ty + j][tx] = in[(size_t)(r0 + ty + j) * C + c0 + tx];
    __syncthreads();
    #pragma unroll
    for (int j = 0; j < 32; j += 8)
        out[(size_t)(c0 + ty + j) * R + r0 + tx] = f2bf(t[tx][ty + j]);
}

// ---------------- GEMM-T: 128x192, BK=64, 2-phase pipeline, 2 blocks/CU ----------------
// C[M][N] = A[M][K] @ BT[N][K]^T, bf16 in, bf16 out. 4 waves (2x2), per-wave 64x96.
// dbuf 2x40KB = 80KB -> 2 blocks/CU = 160KB (full pool).
__global__ __launch_bounds__(256, 2)
void k_gemmT(const u16* __restrict__ A, const u16* __restrict__ BT,
             u16* __restrict__ C, int N, int K) {
    __shared__ char lds[2 * 40960];    // per buf: A @0 (16KB, 128 rows), B @16384 (24KB, 192 rows)

    const int tid  = threadIdx.x;
    const int lane = tid & 63;
    const int lo   = lane & 15;
    const int hi   = lane >> 4;
    const int wave = tid >> 6;
    const int wm   = wave >> 1;        // 0..1 (64-row band)
    const int wn   = wave & 1;         // 0..1 (96-col band)

    // XCD-aware bijective block swizzle (nwg % 8 == 0)
    const int gx   = gridDim.x;
    const int nwg  = gx * gridDim.y;
    const int orig = blockIdx.y * gx + blockIdx.x;
    const int wg   = (orig & 7) * (nwg >> 3) + (orig >> 3);
    const long row0 = (long)(wg / gx) * 128;
    const long col0 = (long)(wg % gx) * 192;

    const int NT = K >> 6;             // BK = 64

    const int srow = tid >> 3;                         // 0..31 (row within 32-row chunk)
    const int gsb  = ((tid & 7) ^ (srow & 7)) << 4;    // pre-swizzled source byte

    auto stage = [&](int t) {
        char* base = lds + (t & 1) * 40960;
        #pragma unroll
        for (int c = 0; c < 4; c++)      // A: 128 rows = 4 chunks
            gload_lds16((const char*)(A + (row0 + c * 32 + srow) * (size_t)K + t * 64) + gsb,
                        base + c * 4096 + tid * 16);
        #pragma unroll
        for (int c = 0; c < 6; c++)      // B: 192 rows = 6 chunks
            gload_lds16((const char*)(BT + (col0 + c * 32 + srow) * (size_t)K + t * 64) + gsb,
                        base + 16384 + c * 4096 + tid * 16);
    };

    f32x4 acc[4][6] = {};

    stage(0);
    asm volatile("s_waitcnt vmcnt(0)" ::: "memory");
    __builtin_amdgcn_s_barrier();

    for (int t = 0; t < NT; t++) {
        if (t + 1 < NT) stage(t + 1);               // issue early: hides under MFMA
        const char* ab = lds + (t & 1) * 40960;
        const char* bb = ab + 16384;
        short8 af[2][4], bf[2][6];
        #pragma unroll
        for (int kk = 0; kk < 2; kk++) {
            #pragma unroll
            for (int m = 0; m < 4; m++) {
                int r = wm * 64 + m * 16 + lo;      // 0..127
                af[kk][m] = *(const short8*)(ab + r * 128 + ((kk * 64 + hi * 16) ^ ((r & 7) << 4)));
            }
            #pragma unroll
            for (int n = 0; n < 6; n++) {
                int r = wn * 96 + n * 16 + lo;      // 0..191
                bf[kk][n] = *(const short8*)(bb + r * 128 + ((kk * 64 + hi * 16) ^ ((r & 7) << 4)));
            }
        }
        #pragma unroll
        for (int m = 0; m < 4; m++)
            #pragma unroll
            for (int n = 0; n < 6; n++)
                acc[m][n] = __builtin_amdgcn_mfma_f32_16x16x32_bf16(af[0][m], bf[0][n], acc[m][n], 0, 0, 0);
        if (t + 1 < NT) {
            asm volatile("s_waitcnt vmcnt(0)" ::: "memory");   // t+1 resident
            __builtin_amdgcn_s_barrier();                      // all reads of buf[t] done
        }
        #pragma unroll
        for (int m = 0; m < 4; m++)
            #pragma unroll
            for (int n = 0; n < 6; n++)
                acc[m][n] = __builtin_amdgcn_mfma_f32_16x16x32_bf16(af[1][m], bf[1][n], acc[m][n], 0, 0, 0);
    }

    // ---- epilogue (bf16 out) ----
    #pragma unroll
    for (int m = 0; m < 4; m++)
        #pragma unroll
        for (int n = 0; n < 6; n++)
            #pragma unroll
            for (int r = 0; r < 4; r++) {
                long row = row0 + wm * 64 + m * 16 + hi * 4 + r;
                long col = col0 + wn * 96 + n * 16 + lo;
                C[row * (size_t)N + col] = f2bf(acc[m][n][r]);
            }
}

// ---------------- GEMM: 128x128, BK=64, 2-phase pipeline (R8) + kk-split ----------------
// Used for GEMM2 (N=1024, 192 doesn't divide). Same mechanism set.
template<bool OUT_BF16>
__global__ __launch_bounds__(256, 2)
void k_gemm2(const u16* __restrict__ A, const u16* __restrict__ BT,
             void* __restrict__ C, int N, int K) {
    __shared__ char lds[2 * 32768];    // per buf: A @0 (16KB), B @16384 (16KB)

    const int tid  = threadIdx.x;
    const int lane = tid & 63;
    const int lo   = lane & 15;
    const int hi   = lane >> 4;
    const int wave = tid >> 6;
    const int wm   = wave >> 1;
    const int wn   = wave & 1;

    const int gx   = gridDim.x;
    const int nwg  = gx * gridDim.y;
    const int orig = blockIdx.y * gx + blockIdx.x;
    const int wg   = (orig & 7) * (nwg >> 3) + (orig >> 3);
    const long row0 = (long)(wg / gx) * 128;
    const long col0 = (long)(wg % gx) * 128;

    const int NT = K >> 6;             // BK = 64

    const int srow = tid >> 3;                         // 0..31 (row within 32-row chunk)
    const int gsb  = ((tid & 7) ^ (srow & 7)) << 4;    // pre-swizzled source byte

    auto stage = [&](int t) {
        char* base = lds + (t & 1) * 32768;
        #pragma unroll
        for (int c = 0; c < 4; c++)
            gload_lds16((const char*)(A + (row0 + c * 32 + srow) * (size_t)K + t * 64) + gsb,
                        base + c * 4096 + tid * 16);
        #pragma unroll
        for (int c = 0; c < 4; c++)
            gload_lds16((const char*)(BT + (col0 + c * 32 + srow) * (size_t)K + t * 64) + gsb,
                        base + 16384 + c * 4096 + tid * 16);
    };

    f32x4 acc[4][4] = {};

    stage(0);
    asm volatile("s_waitcnt vmcnt(0)" ::: "memory");
    __builtin_amdgcn_s_barrier();

    for (int t = 0; t < NT; t++) {
        if (t + 1 < NT) stage(t + 1);               // issue early: hides under MFMA
        const char* ab = lds + (t & 1) * 32768;
        const char* bb = ab + 16384;
        short8 af[2][4], bf[2][4];
        #pragma unroll
        for (int kk = 0; kk < 2; kk++) {
            #pragma unroll
            for (int m = 0; m < 4; m++) {
                int r = wm * 64 + m * 16 + lo;
                af[kk][m] = *(const short8*)(ab + r * 128 + ((kk * 64 + hi * 16) ^ ((r & 7) << 4)));
            }
            #pragma unroll
            for (int n = 0; n < 4; n++) {
                int r = wn * 64 + n * 16 + lo;
                bf[kk][n] = *(const short8*)(bb + r * 128 + ((kk * 64 + hi * 16) ^ ((r & 7) << 4)));
            }
        }
        #pragma unroll
        for (int m = 0; m < 4; m++)
            #pragma unroll
            for (int n = 0; n < 4; n++)
                acc[m][n] = __builtin_amdgcn_mfma_f32_16x16x32_bf16(af[0][m], bf[0][n], acc[m][n], 0, 0, 0);
        if (t + 1 < NT) {
            asm volatile("s_waitcnt vmcnt(0)" ::: "memory");   // t+1 resident
            __builtin_amdgcn_s_barrier();                      // all reads of buf[t] done
        }
        #pragma unroll
        for (int m = 0; m < 4; m++)
            #pragma unroll
            for (int n = 0; n < 4; n++)
                acc[m][n] = __builtin_amdgcn_mfma_f32_16x16x32_bf16(af[1][m], bf[1][n], acc[m][n], 0, 0, 0);
    }

    #pragma unroll
    for (int m = 0; m < 4; m++)
        #pragma unroll
        for (int n = 0; n < 4; n++)
            #pragma unroll
            for (int r = 0; r < 4; r++) {
                long row = row0 + wm * 64 + m * 16 + hi * 4 + r;
                long col = col0 + wn * 64 + n * 16 + lo;
                if constexpr (OUT_BF16)
                    ((u16*)C)[row * (size_t)N + col] = f2bf(acc[m][n][r]);
                else
                    ((float*)C)[row * (size_t)N + col] = acc[m][n][r];
            }
}

// ---------------- Flash attention v5: v4 + T14 issue-early/write-late V + T5 setprio ----
// grid: 1024 blocks (8 qi x 128 bh), longest-first. Block = 4 waves x 32 q-rows = 128 q.
// Per tile: barrier -> ISSUE V global loads(t+1) + K gload_lds(t+1) -> compute(t)
// (HBM latency hides under compute) -> vmcnt(0) -> ds_write V(t+1).
#define SCALE_L2E 0.18033688011112042f  // (1/sqrt(64)) * log2(e)

__global__ __launch_bounds__(256, 2)
void k_attn(const u16* __restrict__ qkv, u16* __restrict__ y) {
    constexpr int S = 1024, E = 1024, TE = 3072;
    __shared__ char alds[2 * 16384];   // per buf: K @0 (8KB, [kv][d] swz), V @8192 ([d][kv] swz)

    const int tid  = threadIdx.x;
    const int lane = tid & 63;
    const int l31  = lane & 31;
    const int hA   = lane >> 5;
    const int wave = tid >> 6;

    const int qi = 7 - (int)(blockIdx.x >> 7);   // longest first
    const int bh = blockIdx.x & 127;
    const int b  = bh >> 4;
    const int h  = bh & 15;
    const int q0 = qi * 128;
    const size_t rowbase = (size_t)b * S;
    const int qg = q0 + wave * 32 + l31;         // this lane's q-row

    short8 qf[4];
    {
        const u16* qp = qkv + (rowbase + qg) * TE + h * 64 + hA * 8;
        #pragma unroll
        for (int kd = 0; kd < 4; kd++) qf[kd] = *(const short8*)(qp + kd * 16);
    }

    f32x16 o0 = {}, o1 = {};
    float ms = -1e30f, lsum = 0.f;

    const int kr0 = (wave << 3) + (lane >> 3);
    const int kcb = (lane & 7) * 16;
    const int vkv = (tid >> 3) * 2;
    const int vdc = (tid & 7) * 8;

    // issue phase: K direct-to-LDS + V global->reg (latency hides under compute)
    auto issue = [&](int t, short8& v0, short8& v1) {
        char* base = alds + (t & 1) * 16384;
        const int kv0 = t * 64;
        #pragma unroll
        for (int it = 0; it < 2; it++) {
            int r = kr0 + it * 32;
            const char* src = (const char*)qkv
                + (((rowbase + kv0 + r) * TE + E + h * 64) << 1) + (kcb ^ swz(r));
            gload_lds16(src, base + wave * 1024 + it * 4096);
        }
        const u16* vsrc = qkv + (rowbase + kv0 + vkv) * TE + 2 * E + h * 64 + vdc;
        v0 = *(const short8*)vsrc;
        v1 = *(const short8*)(vsrc + TE);
    };
    // write phase: V regs -> swizzled LDS (after compute; vmcnt(0) done by caller)
    auto writeV = [&](int t, short8 v0, short8 v1) {
        char* base = alds + (t & 1) * 16384;
        #pragma unroll
        for (int j = 0; j < 8; j++) {
            int d = vdc + j;
            unsigned val = (unsigned)(u16)v0[j] | ((unsigned)(u16)v1[j] << 16);
            *(unsigned*)(base + 8192 + d * 128 + ((vkv * 2) ^ swz(d))) = val;
        }
    };

    const int ntiles = 2 * qi + 2;
    {   // prologue: tile 0 staged fully
        short8 v0, v1;
        issue(0, v0, v1);
        asm volatile("s_waitcnt vmcnt(0)" ::: "memory");
        writeV(0, v0, v1);
    }
    for (int t = 0; t < ntiles; ++t) {
        __syncthreads();                       // buf[t] resident (K vmcnt'd, V lgkm-drained)
        short8 nv0, nv1;
        const bool more = (t + 1 < ntiles);
        if (more) issue(t + 1, nv0, nv1);      // K gload + V reg-loads in flight

        const char* Kt = alds + (t & 1) * 16384;
        const char* Vt = Kt + 8192;
        const int kv0 = t * 64;

        const bool active = (kv0 <= q0 + wave * 32 + 31);   // wave-uniform
        if (active) {
            f32x16 s0 = {}, s1 = {};
            __builtin_amdgcn_s_setprio(1);
            #pragma unroll
            for (int kd = 0; kd < 4; kd++) {
                int r0 = l31, r1 = 32 + l31;
                short8 ka0 = *(const short8*)(Kt + r0 * 128 + ((kd * 32 + hA * 16) ^ swz(r0)));
                short8 ka1 = *(const short8*)(Kt + r1 * 128 + ((kd * 32 + hA * 16) ^ swz(r1)));
                s0 = __builtin_amdgcn_mfma_f32_32x32x16_bf16(ka0, qf[kd], s0, 0, 0, 0);
                s1 = __builtin_amdgcn_mfma_f32_32x32x16_bf16(ka1, qf[kd], s1, 0, 0, 0);
            }
            __builtin_amdgcn_s_setprio(0);

            if (kv0 + 63 > q0 + wave * 32) {
                #pragma unroll
                for (int r = 0; r < 16; r++) {
                    int kvr = kv0 + ((r & 3) + 8 * (r >> 2) + 4 * hA);
                    if (kvr > qg)      s0[r] = -1e30f;
                    if (kvr + 32 > qg) s1[r] = -1e30f;
                }
            }

            float pm = s0[0];
            #pragma unroll
            for (int r = 1; r < 16; r++) pm = fmaxf(pm, s0[r]);
            #pragma unroll
            for (int r = 0; r < 16; r++) pm = fmaxf(pm, s1[r]);
            pm = fmaxf(pm, __shfl_xor(pm, 32));
            float pms = pm * SCALE_L2E;
            if (__any(pms - ms > 8.0f)) {
                float msn = fmaxf(ms, pms);
                float alpha = exp2f(ms - msn);
                ms = msn;
                lsum *= alpha;
                #pragma unroll
                for (int r = 0; r < 16; r++) { o0[r] *= alpha; o1[r] *= alpha; }
            }

            float part = 0.f;
            #pragma unroll
            for (int r = 0; r < 16; r++) {
                float p0 = exp2f(s0[r] * SCALE_L2E - ms);
                float p1 = exp2f(s1[r] * SCALE_L2E - ms);
                s0[r] = p0; s1[r] = p1;
                part += p0 + p1;
            }
            lsum += part + __shfl_xor(part, 32);

            unsigned w0[8], w1[8];
            #pragma unroll
            for (int j = 0; j < 8; j++) {
                asm("v_cvt_pk_bf16_f32 %0, %1, %2" : "=v"(w0[j]) : "v"(s0[2 * j]), "v"(s0[2 * j + 1]));
                asm("v_cvt_pk_bf16_f32 %0, %1, %2" : "=v"(w1[j]) : "v"(s1[2 * j]), "v"(s1[2 * j + 1]));
            }

            __builtin_amdgcn_s_setprio(1);
            #define PV_TILE(W, ST)                                                              \
            {                                                                                   \
                _Pragma("unroll")                                                               \
                for (int kkl = 0; kkl < 2; kkl++) {                                             \
                    unsigned a  = W[4 * kkl],     bsw = W[4 * kkl + 2];                         \
                    unsigned a2 = W[4 * kkl + 1], b2  = W[4 * kkl + 3];                         \
                    swap32(a, bsw); swap32(a2, b2);                                             \
                    union { int4 i; short8 s; } u;                                              \
                    u.i = make_int4((int)a, (int)a2, (int)bsw, (int)b2);                        \
                    {                                                                           \
                        int row = l31;                                                          \
                        short8 va = *(const short8*)(Vt + row * 128                             \
                                      + (((ST) * 64 + kkl * 32 + hA * 16) ^ swz(row)));         \
                        o0 = __builtin_amdgcn_mfma_f32_32x32x16_bf16(va, u.s, o0, 0, 0, 0);     \
                    }                                                                           \
                    {                                                                           \
                        int row = 32 + l31;                                                     \
                        short8 va = *(const short8*)(Vt + row * 128                             \
                                      + (((ST) * 64 + kkl * 32 + hA * 16) ^ swz(row)));         \
                        o1 = __builtin_amdgcn_mfma_f32_32x32x16_bf16(va, u.s, o1, 0, 0, 0);     \
                    }                                                                           \
                }                                                                               \
            }
            PV_TILE(w0, 0)
            PV_TILE(w1, 1)
            #undef PV_TILE
            __builtin_amdgcn_s_setprio(0);
        }

        if (more) {
            asm volatile("s_waitcnt vmcnt(0)" ::: "memory");   // V regs + K gload arrived
            writeV(t + 1, nv0, nv1);                           // lgkm drained by next barrier
        }
    }

    // ---- epilogue: normalize, transpose O^T -> O via LDS, store bf16 ----
    __syncthreads();   // all tiles done reading K/V buffers
    float rinv = 1.0f / lsum;
    char* Ot = alds + wave * 4096;     // 32 rows x 64 d per wave (4KB), wave-private
    const int X = (l31 & 7) << 4;
    #pragma unroll
    for (int rq = 0; rq < 4; rq++) {
        u16x4 pk0, pk1;
        #pragma unroll
        for (int j = 0; j < 4; j++) {
            pk0[j] = f2bf(o0[4 * rq + j] * rinv);    // d = 8*rq + 4*hA + j
            pk1[j] = f2bf(o1[4 * rq + j] * rinv);    // d = 32 + 8*rq + 4*hA + j
        }
        *(u16x4*)(Ot + l31 * 128 + ((16 * rq + 8 * hA) ^ X))      = pk0;
        *(u16x4*)(Ot + l31 * 128 + ((64 + 16 * rq + 8 * hA) ^ X)) = pk1;
    }
    __syncthreads();
    #pragma unroll
    for (int p = 0; p < 4; p++) {
        int row = p * 8 + (lane >> 3);               // 0..31 within wave's tile
        int cc  = lane & 7;                          // 16B chunk (8 d-elems)
        short8 vv = *(const short8*)(Ot + row * 128 + ((cc * 16) ^ ((row & 7) << 4)));
        *(short8*)(y + (rowbase + q0 + wave * 32 + row) * E + h * 64 + cc * 8) = vv;
    }
}

// ---------------- launch ----------------
extern "C" void kernel_launch(void* const* d_in, const int* in_sizes, int n_in,
                              void* d_out, int out_size, void* d_ws, size_t ws_size,
                              hipStream_t stream) {
    const float* x     = (const float*)d_in[0];   // [8,1024,1024]
    const float* Wattn = (const float*)d_in[1];   // [1024,3072]
    const float* Wproj = (const float*)d_in[2];   // [1024,1024]
    float* out = (float*)d_out;                   // [8,1024,1024] fp32

    char* ws = (char*)d_ws;
    u16* buf0 = (u16*)ws;                                  // x_bf16, later y_bf16 (16.78 MB)
    u16* wT   = (u16*)(ws + 16777216);                     // W_attn^T bf16 (6.29 MB)
    u16* qkv  = (u16*)(ws + 16777216 + 6291456);           // [8192][3072] bf16 (50.3 MB)
    const size_t wpT_off = 16777216ull + 6291456 + 50331648;
    const bool fused_wp = ws_size >= wpT_off + 2097152;    // room for W_proj^T?
    u16* wpT  = fused_wp ? (u16*)(ws + wpT_off) : wT;      // fallback: reuse wT

    // fused prep: x->bf16 + W_attn^T (+ W_proj^T when buffer space allows)
    k_prep<<<fused_wp ? 6144 : 5120, 256, 0, stream>>>(x, Wattn, Wproj, buf0, wT, wpT);
    // qkv = x @ W_attn   (bf16 out): 128x192 tile, grid 16x64 = 1024 wgs, 2 rounds exact
    k_gemmT<<<dim3(3072 / 192, 8192 / 128), 256, 0, stream>>>(buf0, wT, qkv, 3072, 1024);
    if (!fused_wp) {
        // fallback: W_proj^T -> wT after GEMM1 (old R14 path)
        k_transpose_bf<<<dim3(1024 / 32, 1024 / 32), dim3(32, 8), 0, stream>>>(Wproj, wT, 1024, 1024);
    }
    // flash attention -> y (reuses buf0)
    k_attn<<<dim3(1024), 256, 0, stream>>>(qkv, buf0);
    // out = y @ W_proj  (fp32 out): 128x128 2-phase, grid 8x64 = 512 wgs
    k_gemm2<false><<<dim3(1024 / 128, 8192 / 128), 256, 0, stream>>>(buf0, wpT, out, 1024, 1024);
}